// Round 13
// baseline (1849.155 us; speedup 1.0000x reference)
//
#include <hip/hip_runtime.h>

#define NLEFT  100000
#define NRIGHT 100000
#define NTOT   200000
#define NEDGE  1000000
#define HD     64
#define BNEPS  1e-5f
#define BSH    9
#define NBKT   196   // ceil(100000 / 512)

typedef __attribute__((ext_vector_type(8))) short bfrag8;
typedef __attribute__((ext_vector_type(4))) float facc4;

__device__ inline unsigned short f2bf(float f) {
  unsigned u = __float_as_uint(f);
  u = u + 0x7fffu + ((u >> 16) & 1u);   // RNE
  return (unsigned short)(u >> 16);
}
__device__ inline float bf2f(unsigned short u) {
  return __uint_as_float((unsigned)u << 16);
}

// ---- converted-weight region layout (ushorts, per layer; see wconv_kernel) ----
#define WC_G1    0        // [96][192]  l2^T rows 0-31, nn2_w1^T rows 32-95
#define WC_G2    18432    // [32][192]  l4^T   (l3^T follows contiguously)
#define WC_G3    24576    // [32][192]  l3^T
#define WC_NN2W2 30720    // [64][64]
#define WC_M2    34816    // [96][64]   nn1_w1^T rows 0-63, l1^T rows 64-95
#define WC_NN1W2 40960    // [64][64]
#define WC_OUTW1 45056    // [64][128]
#define WC_OUTW2 53248    // [64][64]
#define WC_PER_L 57344

// ---------------- init ----------------

__global__ __launch_bounds__(256) void init_kernel(const float* __restrict__ xs,
                                                   float* __restrict__ out,
                                                   unsigned short* __restrict__ outbf,
                                                   float* __restrict__ st, int nst,
                                                   int* __restrict__ cl, int* __restrict__ cr,
                                                   int* __restrict__ curl, int* __restrict__ curr) {
  size_t ng = (size_t)NTOT * HD / 4;
  for (size_t i = (size_t)blockIdx.x * blockDim.x + threadIdx.x; i < ng;
       i += (size_t)gridDim.x * blockDim.x) {
    float4 v = reinterpret_cast<const float4*>(xs)[i];
    reinterpret_cast<float4*>(out)[i] = v;
    ushort4 p;
    p.x = f2bf(v.x); p.y = f2bf(v.y); p.z = f2bf(v.z); p.w = f2bf(v.w);
    reinterpret_cast<ushort4*>(outbf)[i] = p;
  }
  for (int i = blockIdx.x * blockDim.x + threadIdx.x; i < NLEFT;
       i += gridDim.x * blockDim.x) {
    cl[i] = 0; curl[i] = 0; cr[i] = 0; curr[i] = 0;
    if (i < nst) st[i] = 0.f;
  }
}

__global__ __launch_bounds__(256) void count_kernel(const int* __restrict__ src,
                                                    const int* __restrict__ dst,
                                                    int* __restrict__ cl, int* __restrict__ cr) {
  for (int e = blockIdx.x * blockDim.x + threadIdx.x; e < NEDGE;
       e += gridDim.x * blockDim.x) {
    atomicAdd(&cl[src[e]], 1);
    atomicAdd(&cr[dst[e]], 1);
  }
}

// ---------------- weight convert+transpose: fp32 [K][N] -> bf16 [N][K] ----------------

__global__ __launch_bounds__(256) void wconv_kernel(const float* __restrict__ l2w,
                                                    const float* __restrict__ nn2w1,
                                                    const float* __restrict__ l4w,
                                                    const float* __restrict__ l3w,
                                                    const float* __restrict__ nn2w2,
                                                    const float* __restrict__ nn1w1,
                                                    const float* __restrict__ l1w,
                                                    const float* __restrict__ nn1w2,
                                                    const float* __restrict__ outw1,
                                                    const float* __restrict__ outw2,
                                                    unsigned short* __restrict__ dst) {
  for (int idx = blockIdx.x * 256 + threadIdx.x; idx < 2 * WC_PER_L;
       idx += gridDim.x * 256) {
    int l = idx / WC_PER_L;
    int r = idx - l * WC_PER_L;
    const float* src; int N, n, k;
    if (r < WC_G2) {
      n = r / 192; k = r - n * 192;
      if (n < 32) { src = l2w + (size_t)l * 192 * 32; N = 32; }
      else        { src = nn2w1 + (size_t)l * 192 * 64; N = 64; n -= 32; }
    } else if (r < WC_G3) {
      int rr = r - WC_G2; n = rr / 192; k = rr - n * 192;
      src = l4w + (size_t)l * 192 * 32; N = 32;
    } else if (r < WC_NN2W2) {
      int rr = r - WC_G3; n = rr / 192; k = rr - n * 192;
      src = l3w + (size_t)l * 192 * 32; N = 32;
    } else if (r < WC_M2) {
      int rr = r - WC_NN2W2; n = rr / 64; k = rr - n * 64;
      src = nn2w2 + (size_t)l * 64 * 64; N = 64;
    } else if (r < WC_NN1W2) {
      int rr = r - WC_M2; n = rr / 64; k = rr - n * 64;
      if (n < 64) { src = nn1w1 + (size_t)l * 64 * 64; N = 64; }
      else        { src = l1w + (size_t)l * 64 * 32; N = 32; n -= 64; }
    } else if (r < WC_OUTW1) {
      int rr = r - WC_NN1W2; n = rr / 64; k = rr - n * 64;
      src = nn1w2 + (size_t)l * 64 * 64; N = 64;
    } else if (r < WC_OUTW2) {
      int rr = r - WC_OUTW1; n = rr / 128; k = rr - n * 128;
      src = outw1 + (size_t)l * 128 * 64; N = 64;
    } else {
      int rr = r - WC_OUTW2; n = rr / 64; k = rr - n * 64;
      src = outw2 + (size_t)l * 64 * 64; N = 64;
    }
    dst[idx] = f2bf(src[(size_t)k * N + n]);
  }
}

// ---------------- exclusive scan ----------------

__global__ __launch_bounds__(256) void scan1_kernel(const int* __restrict__ cnt, int n,
                                                    int* __restrict__ partial) {
  __shared__ int tmp[256];
  int i = blockIdx.x * 256 + threadIdx.x;
  tmp[threadIdx.x] = (i < n) ? cnt[i] : 0;
  __syncthreads();
  for (int s = 128; s > 0; s >>= 1) {
    if (threadIdx.x < s) tmp[threadIdx.x] += tmp[threadIdx.x + s];
    __syncthreads();
  }
  if (threadIdx.x == 0) partial[blockIdx.x] = tmp[0];
}

__global__ __launch_bounds__(1024) void scan2_kernel(int* __restrict__ partial, int nb) {
  __shared__ int tmp[1024];
  int t = threadIdx.x;
  int v = (t < nb) ? partial[t] : 0;
  tmp[t] = v;
  __syncthreads();
  for (int off = 1; off < 1024; off <<= 1) {
    int x = tmp[t];
    int add = (t >= off) ? tmp[t - off] : 0;
    __syncthreads();
    tmp[t] = x + add;
    __syncthreads();
  }
  if (t < nb) partial[t] = tmp[t] - v;
}

__global__ __launch_bounds__(256) void scan3_kernel(const int* __restrict__ cnt, int n,
                                                    const int* __restrict__ partial,
                                                    int* __restrict__ offs) {
  __shared__ int tmp[256];
  int t = threadIdx.x;
  int i = blockIdx.x * 256 + t;
  int v = (i < n) ? cnt[i] : 0;
  tmp[t] = v;
  __syncthreads();
  for (int off = 1; off < 256; off <<= 1) {
    int x = tmp[t];
    int add = (t >= off) ? tmp[t - off] : 0;
    __syncthreads();
    tmp[t] = x + add;
    __syncthreads();
  }
  if (i < n) offs[i] = tmp[t] - v + partial[blockIdx.x];
  if (i == 0) offs[n] = NEDGE;
}

// ---------------- binned CSR fill (3 phases; kills random-RMW write amplification) ----------------

// phase 0: per-bucket exclusive offsets (cursor init) from the per-key counts
__global__ __launch_bounds__(256) void bucket_kernel(const int* __restrict__ cntL,
                                                     const int* __restrict__ cntR,
                                                     int* __restrict__ bcurL,
                                                     int* __restrict__ bcurR) {
  __shared__ int bl[NBKT], br[NBKT];
  int t = threadIdx.x;
  if (t < NBKT) {
    int sL = 0, sR = 0;
    int k0 = t << BSH;
    int k1 = k0 + (1 << BSH); if (k1 > NLEFT) k1 = NLEFT;
    for (int k = k0; k < k1; k++) { sL += cntL[k]; sR += cntR[k]; }
    bl[t] = sL; br[t] = sR;
  }
  __syncthreads();
  if (t == 0) {
    int aL = 0, aR = 0;
    for (int b = 0; b < NBKT; b++) {
      int cl = bl[b], cr = br[b];
      bcurL[b] = aL; bcurR[b] = aR;
      aL += cl; aR += cr;
    }
  }
}

// phase 1: stream edges, append (key,val) pairs into per-bucket segments.
// Writes are 196 sequential tails -> lines fill in L2 before eviction.
__global__ __launch_bounds__(256) void bin_kernel(const int* __restrict__ src,
                                                  const int* __restrict__ dst,
                                                  int* __restrict__ bcurL,
                                                  int* __restrict__ bcurR,
                                                  int2* __restrict__ binL,
                                                  int2* __restrict__ binR) {
  for (int e = blockIdx.x * blockDim.x + threadIdx.x; e < NEDGE;
       e += gridDim.x * blockDim.x) {
    int s = src[e], d = dst[e];
    int pL = atomicAdd(&bcurL[s >> BSH], 1);
    binL[pL] = make_int2(s, d);
    int pR = atomicAdd(&bcurR[d >> BSH], 1);
    binR[pR] = make_int2(d, s);
  }
}

// phase 2: one block per bucket; scatter within the bucket's ~20KB adj window
// (offs/cur window 2KB) -> all RMW L2-resident, lines fully dirtied.
__global__ __launch_bounds__(256) void scatter_kernel(const int2* __restrict__ bin,
                                                      const int* __restrict__ bcur,
                                                      const int* __restrict__ offs,
                                                      int* __restrict__ cur,
                                                      int* __restrict__ adj) {
  int b = blockIdx.x;
  int lo = (b == 0) ? 0 : bcur[b - 1];
  int hi = bcur[b];
  for (int i = lo + threadIdx.x; i < hi; i += 256) {
    int2 p = bin[i];
    int pos = atomicAdd(&cur[p.x], 1);
    adj[offs[p.x] + pos] = p.y;
  }
}

// ---------------- fused gather + MFMA (persistent, pre-converted weights) ----------------

template <int N1, int N2, bool SRCNORM>
__global__ __launch_bounds__(512) void gmm_mfma(const unsigned short* __restrict__ mat,
                                                const int* __restrict__ offs,
                                                const int* __restrict__ adj,
                                                int nseg,
                                                const float* __restrict__ st_src, float inv_src,
                                                const unsigned short* __restrict__ Wbf,
                                                const float* __restrict__ B1,
                                                unsigned short* __restrict__ Y1,
                                                float* __restrict__ st1,
                                                const float* __restrict__ B2,
                                                unsigned short* __restrict__ Y2,
                                                float* __restrict__ st2) {
  constexpr int K    = 192;
  constexpr int LDX  = 200;
  constexpr int SEGS = 32;
  constexpr int NT   = N1 + N2;
  constexpr int CTT  = NT / 16;
  constexpr int CTW  = (CTT >= 6) ? 2 : 1;
  constexpr int NGRP = CTT / CTW;
  constexpr int NWM  = 2 * NGRP;
  __shared__ alignas(16) unsigned short xl[SEGS * LDX];
  __shared__ alignas(16) unsigned short wl[NT * LDX];
  __shared__ float bl[NT];
  __shared__ float ldsS[NT], ldsQ[NT];

  int tid = threadIdx.x;
  for (int i = tid; i < NT * 24; i += 512) {
    int n = i / 24, kk = (i - n * 24) * 8;
    *reinterpret_cast<bfrag8*>(&wl[n * LDX + kk]) =
        *reinterpret_cast<const bfrag8*>(&Wbf[n * 192 + kk]);
  }
  for (int i = tid; i < N1; i += 512) bl[i] = B1[i];
  if constexpr (N2 > 0)
    for (int i = tid; i < N2; i += 512) bl[N1 + i] = B2[i];
  if (tid < NT) { ldsS[tid] = 0.f; ldsQ[tid] = 0.f; }

  int wave = tid >> 6;
  int lane = tid & 63;
  int half = lane >> 5;
  int c0   = (lane & 31) * 2;

  float nm0 = 0.f, nm1 = 0.f, ns0 = 1.f, ns1 = 1.f;
  if (SRCNORM) {
    float m0 = st_src[c0] * inv_src, m1 = st_src[c0 + 1] * inv_src;
    float v0 = st_src[64 + c0] * inv_src - m0 * m0;
    float v1 = st_src[64 + c0 + 1] * inv_src - m1 * m1;
    nm0 = m0; nm1 = m1;
    ns0 = rsqrtf(fmaxf(v0, 0.f) + BNEPS);
    ns1 = rsqrtf(fmaxf(v1, 0.f) + BNEPS);
  }

  int lr  = lane & 15;
  int lk  = (lane >> 4) * 8;
  int lj4 = (lane >> 4) * 4;
  int rowtile = wave & 1;
  int colgrp  = wave >> 1;
  int rowbase = rowtile * 16;

  float sacc[CTW], qacc[CTW];
#pragma unroll
  for (int ct = 0; ct < CTW; ct++) { sacc[ct] = 0.f; qacc[ct] = 0.f; }

  int tiles = (nseg + SEGS - 1) / SEGS;
  for (int t = blockIdx.x; t < tiles; t += gridDim.x) {
    __syncthreads();
    int segbase = t * SEGS + wave * 4;
    for (int s = 0; s < 4; s++) {
      int seg = segbase + s;
      int row = wave * 4 + s;
      float s0 = 0.f, s1 = 0.f, m0 = -INFINITY, m1 = -INFINITY;
      int cdeg = 0;
      if (seg < nseg) {
        int b = offs[seg], e = offs[seg + 1];
        cdeg = e - b;
        for (int jb = b + half; jb < e; jb += 16) {
          unsigned pk[8];
#pragma unroll
          for (int u = 0; u < 8; u++) {
            int j = jb + 2 * u;
            pk[u] = 0;
            if (j < e) {
              int g = adj[j];
              pk[u] = *reinterpret_cast<const unsigned*>(&mat[(size_t)g * HD + c0]);
            }
          }
#pragma unroll
          for (int u = 0; u < 8; u++) {
            int j = jb + 2 * u;
            if (j < e) {
              float v0 = __uint_as_float(pk[u] << 16);
              float v1 = __uint_as_float(pk[u] & 0xffff0000u);
              if (SRCNORM) {
                v0 = fmaxf((v0 - nm0) * ns0, 0.f);
                v1 = fmaxf((v1 - nm1) * ns1, 0.f);
              }
              s0 += v0; s1 += v1;
              m0 = fmaxf(m0, v0); m1 = fmaxf(m1, v1);
            }
          }
        }
        s0 += __shfl_xor(s0, 32);
        s1 += __shfl_xor(s1, 32);
        m0 = fmaxf(m0, __shfl_xor(m0, 32));
        m1 = fmaxf(m1, __shfl_xor(m1, 32));
      }
      float inv = 1.f / fmaxf((float)cdeg, 1.f);
      if (cdeg == 0) { m0 = 0.f; m1 = 0.f; s0 = 0.f; s1 = 0.f; }
      if (half == 0) {
        unsigned sp = (unsigned)f2bf(s0) | ((unsigned)f2bf(s1) << 16);
        unsigned mp = (unsigned)f2bf(m0) | ((unsigned)f2bf(m1) << 16);
        *reinterpret_cast<unsigned*>(&xl[row * LDX + c0])       = sp;
        *reinterpret_cast<unsigned*>(&xl[row * LDX + 128 + c0]) = mp;
      } else {
        unsigned ap = (unsigned)f2bf(s0 * inv) | ((unsigned)f2bf(s1 * inv) << 16);
        *reinterpret_cast<unsigned*>(&xl[row * LDX + 64 + c0]) = ap;
      }
    }
    __syncthreads();

    if (wave < NWM) {
      facc4 acc[CTW];
#pragma unroll
      for (int ct = 0; ct < CTW; ct++) acc[ct] = (facc4){0.f, 0.f, 0.f, 0.f};
#pragma unroll
      for (int kt = 0; kt < K / 32; kt++) {
        bfrag8 a = *reinterpret_cast<const bfrag8*>(&xl[(rowbase + lr) * LDX + kt * 32 + lk]);
#pragma unroll
        for (int ct = 0; ct < CTW; ct++) {
          bfrag8 b = *reinterpret_cast<const bfrag8*>(
              &wl[((colgrp * CTW + ct) * 16 + lr) * LDX + kt * 32 + lk]);
          acc[ct] = __builtin_amdgcn_mfma_f32_16x16x32_bf16(a, b, acc[ct], 0, 0, 0);
        }
      }
#pragma unroll
      for (int ct = 0; ct < CTW; ct++) {
        int col = (colgrp * CTW + ct) * 16 + lr;
        float bias = bl[col];
#pragma unroll
        for (int j = 0; j < 4; j++) {
          int grow = t * SEGS + rowbase + lj4 + j;
          if (grow < nseg) {
            float v = acc[ct][j] + bias;
            if (col < N1) Y1[(size_t)grow * N1 + col] = f2bf(v);
            else          Y2[(size_t)grow * N2 + (col - N1)] = f2bf(v);
            sacc[ct] += v; qacc[ct] += v * v;
          }
        }
      }
    }
  }

  __syncthreads();
  if (wave < NWM) {
#pragma unroll
    for (int ct = 0; ct < CTW; ct++) {
      int col = (colgrp * CTW + ct) * 16 + lr;
      atomicAdd(&ldsS[col], sacc[ct]);
      atomicAdd(&ldsQ[col], qacc[ct]);
    }
  }
  __syncthreads();
  if (tid < NT) {
    if (tid < N1) {
      atomicAdd(&st1[tid], ldsS[tid]);
      atomicAdd(&st1[N1 + tid], ldsQ[tid]);
    } else {
      atomicAdd(&st2[tid - N1], ldsS[tid]);
      atomicAdd(&st2[N2 + (tid - N1)], ldsQ[tid]);
    }
  }
}

// ---------------- dual-SOURCE fused gather + MFMA: two mats, one adjacency ----------------

__global__ __launch_bounds__(512) void gmm2_mfma(const unsigned short* __restrict__ matA,
                                                 const float* __restrict__ stA, float invA,
                                                 const unsigned short* __restrict__ matB,
                                                 const float* __restrict__ stB, float invB,
                                                 const int* __restrict__ offs,
                                                 const int* __restrict__ adj,
                                                 int nseg,
                                                 const unsigned short* __restrict__ Wbf,
                                                 const float* __restrict__ BA,
                                                 const float* __restrict__ BB,
                                                 unsigned short* __restrict__ YA,
                                                 float* __restrict__ st1,
                                                 unsigned short* __restrict__ YB,
                                                 float* __restrict__ st2) {
  constexpr int K = 192, LDX = 200, SEGS = 32;
  __shared__ alignas(16) unsigned short xlA[SEGS * LDX];
  __shared__ alignas(16) unsigned short xlB[SEGS * LDX];
  __shared__ alignas(16) unsigned short wl[64 * LDX];
  __shared__ float bl[64];
  __shared__ float ldsS[64], ldsQ[64];

  int tid = threadIdx.x;
  for (int i = tid; i < 64 * 24; i += 512) {
    int n = i / 24, kk = (i - n * 24) * 8;
    *reinterpret_cast<bfrag8*>(&wl[n * LDX + kk]) =
        *reinterpret_cast<const bfrag8*>(&Wbf[n * 192 + kk]);
  }
  if (tid < 32) bl[tid] = BA[tid];
  else if (tid < 64) bl[tid] = BB[tid - 32];
  if (tid < 64) { ldsS[tid] = 0.f; ldsQ[tid] = 0.f; }

  int wave = tid >> 6;
  int lane = tid & 63;
  int half = lane >> 5;
  int c0   = (lane & 31) * 2;

  float nmA0, nmA1, nsA0, nsA1, nmB0, nmB1, nsB0, nsB1;
  {
    float m0 = stA[c0] * invA, m1 = stA[c0 + 1] * invA;
    float v0 = stA[64 + c0] * invA - m0 * m0;
    float v1 = stA[64 + c0 + 1] * invA - m1 * m1;
    nmA0 = m0; nmA1 = m1;
    nsA0 = rsqrtf(fmaxf(v0, 0.f) + BNEPS);
    nsA1 = rsqrtf(fmaxf(v1, 0.f) + BNEPS);
    m0 = stB[c0] * invB; m1 = stB[c0 + 1] * invB;
    v0 = stB[64 + c0] * invB - m0 * m0;
    v1 = stB[64 + c0 + 1] * invB - m1 * m1;
    nmB0 = m0; nmB1 = m1;
    nsB0 = rsqrtf(fmaxf(v0, 0.f) + BNEPS);
    nsB1 = rsqrtf(fmaxf(v1, 0.f) + BNEPS);
  }

  int lr  = lane & 15;
  int lk  = (lane >> 4) * 8;
  int lj4 = (lane >> 4) * 4;
  int grp     = wave >> 2;
  int rowtile = wave & 1;
  int ctile   = (wave >> 1) & 1;
  int rowbase = rowtile * 16;

  float sacc = 0.f, qacc = 0.f;

  int tiles = (nseg + SEGS - 1) / SEGS;
  for (int t = blockIdx.x; t < tiles; t += gridDim.x) {
    __syncthreads();
    int segbase = t * SEGS + wave * 4;
    for (int s = 0; s < 4; s++) {
      int seg = segbase + s;
      int row = wave * 4 + s;
      float sA0 = 0.f, sA1 = 0.f, mA0 = -INFINITY, mA1 = -INFINITY;
      float sB0 = 0.f, sB1 = 0.f, mB0 = -INFINITY, mB1 = -INFINITY;
      int cdeg = 0;
      if (seg < nseg) {
        int b = offs[seg], e = offs[seg + 1];
        cdeg = e - b;
        for (int jb = b + half; jb < e; jb += 16) {
          unsigned pkA[8], pkB[8];
#pragma unroll
          for (int u = 0; u < 8; u++) {
            int j = jb + 2 * u;
            pkA[u] = 0; pkB[u] = 0;
            if (j < e) {
              int g = adj[j];
              pkA[u] = *reinterpret_cast<const unsigned*>(&matA[(size_t)g * HD + c0]);
              pkB[u] = *reinterpret_cast<const unsigned*>(&matB[(size_t)g * HD + c0]);
            }
          }
#pragma unroll
          for (int u = 0; u < 8; u++) {
            int j = jb + 2 * u;
            if (j < e) {
              float a0 = fmaxf((__uint_as_float(pkA[u] << 16) - nmA0) * nsA0, 0.f);
              float a1 = fmaxf((__uint_as_float(pkA[u] & 0xffff0000u) - nmA1) * nsA1, 0.f);
              float b0 = fmaxf((__uint_as_float(pkB[u] << 16) - nmB0) * nsB0, 0.f);
              float b1 = fmaxf((__uint_as_float(pkB[u] & 0xffff0000u) - nmB1) * nsB1, 0.f);
              sA0 += a0; sA1 += a1; mA0 = fmaxf(mA0, a0); mA1 = fmaxf(mA1, a1);
              sB0 += b0; sB1 += b1; mB0 = fmaxf(mB0, b0); mB1 = fmaxf(mB1, b1);
            }
          }
        }
        sA0 += __shfl_xor(sA0, 32);
        sA1 += __shfl_xor(sA1, 32);
        mA0 = fmaxf(mA0, __shfl_xor(mA0, 32));
        mA1 = fmaxf(mA1, __shfl_xor(mA1, 32));
        sB0 += __shfl_xor(sB0, 32);
        sB1 += __shfl_xor(sB1, 32);
        mB0 = fmaxf(mB0, __shfl_xor(mB0, 32));
        mB1 = fmaxf(mB1, __shfl_xor(mB1, 32));
      }
      float inv = 1.f / fmaxf((float)cdeg, 1.f);
      if (cdeg == 0) { mA0 = 0.f; mA1 = 0.f; mB0 = 0.f; mB1 = 0.f;
                       sA0 = 0.f; sA1 = 0.f; sB0 = 0.f; sB1 = 0.f; }
      if (half == 0) {
        *reinterpret_cast<unsigned*>(&xlA[row * LDX + c0]) =
            (unsigned)f2bf(sA0) | ((unsigned)f2bf(sA1) << 16);
        *reinterpret_cast<unsigned*>(&xlA[row * LDX + 128 + c0]) =
            (unsigned)f2bf(mA0) | ((unsigned)f2bf(mA1) << 16);
        *reinterpret_cast<unsigned*>(&xlB[row * LDX + c0]) =
            (unsigned)f2bf(sB0) | ((unsigned)f2bf(sB1) << 16);
        *reinterpret_cast<unsigned*>(&xlB[row * LDX + 128 + c0]) =
            (unsigned)f2bf(mB0) | ((unsigned)f2bf(mB1) << 16);
      } else {
        *reinterpret_cast<unsigned*>(&xlA[row * LDX + 64 + c0]) =
            (unsigned)f2bf(sA0 * inv) | ((unsigned)f2bf(sA1 * inv) << 16);
        *reinterpret_cast<unsigned*>(&xlB[row * LDX + 64 + c0]) =
            (unsigned)f2bf(sB0 * inv) | ((unsigned)f2bf(sB1 * inv) << 16);
      }
    }
    __syncthreads();

    {
      const unsigned short* xl = grp ? xlB : xlA;
      facc4 acc = (facc4){0.f, 0.f, 0.f, 0.f};
#pragma unroll
      for (int kt = 0; kt < K / 32; kt++) {
        bfrag8 a = *reinterpret_cast<const bfrag8*>(&xl[(rowbase + lr) * LDX + kt * 32 + lk]);
        bfrag8 b = *reinterpret_cast<const bfrag8*>(
            &wl[(grp * 32 + ctile * 16 + lr) * LDX + kt * 32 + lk]);
        acc = __builtin_amdgcn_mfma_f32_16x16x32_bf16(a, b, acc, 0, 0, 0);
      }
      int col = ctile * 16 + lr;
      float bias = bl[grp * 32 + col];
      unsigned short* Y = grp ? YB : YA;
#pragma unroll
      for (int j = 0; j < 4; j++) {
        int grow = t * SEGS + rowbase + lj4 + j;
        if (grow < nseg) {
          float v = acc[j] + bias;
          Y[(size_t)grow * 32 + col] = f2bf(v);
          sacc += v; qacc += v * v;
        }
      }
    }
  }

  __syncthreads();
  atomicAdd(&ldsS[grp * 32 + ctile * 16 + lr], sacc);
  atomicAdd(&ldsQ[grp * 32 + ctile * 16 + lr], qacc);
  __syncthreads();
  if (tid < 64) {
    if (tid < 32) {
      atomicAdd(&st1[tid], ldsS[tid]);
      atomicAdd(&st1[32 + tid], ldsQ[tid]);
    } else {
      atomicAdd(&st2[tid - 32], ldsS[tid]);
      atomicAdd(&st2[32 + (tid - 32)], ldsQ[tid]);
    }
  }
}

// ---------------- MFMA matmul (pre-converted weights) ----------------

template <int K, int N, int ROWS, bool NIN>
__global__ __launch_bounds__(256) void mm_mfma(const unsigned short* __restrict__ X,
                                               const unsigned short* __restrict__ Wbf,
                                               const float* __restrict__ Bv,
                                               unsigned short* __restrict__ Y, int M,
                                               float* __restrict__ st_out,
                                               const float* __restrict__ st_in, float inv_m) {
  constexpr int LDX = K + 8;
  constexpr int RT  = ROWS / 64;
  constexpr int CT  = N / 16;
  constexpr int KV  = K / 8;
  __shared__ alignas(16) unsigned short xl[ROWS * LDX];
  __shared__ alignas(16) unsigned short wl[N * LDX];
  __shared__ float bl[N];
  __shared__ float nmean[K], nscal[K];
  __shared__ float ldsS[N], ldsQ[N];

  int tid = threadIdx.x;
  for (int i = tid; i < N * KV; i += 256) {
    int n = i / KV, kk = (i - n * KV) * 8;
    *reinterpret_cast<bfrag8*>(&wl[n * LDX + kk]) =
        *reinterpret_cast<const bfrag8*>(&Wbf[n * K + kk]);
  }
  for (int i = tid; i < N; i += 256) bl[i] = Bv[i];
  if (NIN) {
    for (int i = tid; i < K; i += 256) {
      float m = st_in[i] * inv_m;
      float v = st_in[K + i] * inv_m - m * m;
      nmean[i] = m;
      nscal[i] = rsqrtf(fmaxf(v, 0.f) + BNEPS);
    }
  }
  if (tid < N) { ldsS[tid] = 0.f; ldsQ[tid] = 0.f; }

  int lane = tid & 63;
  int wv   = tid >> 6;
  int lr   = lane & 15;
  int lk   = (lane >> 4) * 8;
  int lj4  = (lane >> 4) * 4;
  int rowbase = wv * (RT * 16);

  float sc[CT], sq[CT];
#pragma unroll
  for (int c = 0; c < CT; c++) { sc[c] = 0.f; sq[c] = 0.f; }

  int tiles = (M + ROWS - 1) / ROWS;
  for (int t = blockIdx.x; t < tiles; t += gridDim.x) {
    int r0 = t * ROWS;
    __syncthreads();
    for (int i = tid * 8; i < ROWS * K; i += 2048) {
      int r = i / K, c = i - r * K;
      int row = r0 + r;
      bfrag8 v = {0, 0, 0, 0, 0, 0, 0, 0};
      if (row < M) {
        v = *reinterpret_cast<const bfrag8*>(X + (size_t)row * K + c);
        if (NIN) {
#pragma unroll
          for (int j = 0; j < 8; j++) {
            float f = bf2f((unsigned short)v[j]);
            f = fmaxf((f - nmean[c + j]) * nscal[c + j], 0.f);
            v[j] = (short)f2bf(f);
          }
        }
      }
      *reinterpret_cast<bfrag8*>(&xl[r * LDX + c]) = v;
    }
    __syncthreads();

    facc4 acc[RT][CT];
#pragma unroll
    for (int rt = 0; rt < RT; rt++)
#pragma unroll
      for (int ct = 0; ct < CT; ct++) acc[rt][ct] = (facc4){0.f, 0.f, 0.f, 0.f};

#pragma unroll
    for (int kt = 0; kt < K / 32; kt++) {
      bfrag8 a[RT], b[CT];
#pragma unroll
      for (int rt = 0; rt < RT; rt++)
        a[rt] = *reinterpret_cast<const bfrag8*>(&xl[(rowbase + rt * 16 + lr) * LDX + kt * 32 + lk]);
#pragma unroll
      for (int ct = 0; ct < CT; ct++)
        b[ct] = *reinterpret_cast<const bfrag8*>(&wl[(ct * 16 + lr) * LDX + kt * 32 + lk]);
#pragma unroll
      for (int rt = 0; rt < RT; rt++)
#pragma unroll
        for (int ct = 0; ct < CT; ct++)
          acc[rt][ct] = __builtin_amdgcn_mfma_f32_16x16x32_bf16(a[rt], b[ct], acc[rt][ct], 0, 0, 0);
    }

#pragma unroll
    for (int rt = 0; rt < RT; rt++) {
#pragma unroll
      for (int ct = 0; ct < CT; ct++) {
        int col = ct * 16 + lr;
        float bcol = bl[col];
#pragma unroll
        for (int j = 0; j < 4; j++) {
          int row = r0 + rowbase + rt * 16 + lj4 + j;
          if (row < M) {
            float v = acc[rt][ct][j] + bcol;
            Y[(size_t)row * N + col] = f2bf(v);
            sc[ct] += v; sq[ct] += v * v;
          }
        }
      }
    }
  }

  __syncthreads();
#pragma unroll
  for (int ct = 0; ct < CT; ct++) {
    atomicAdd(&ldsS[ct * 16 + lr], sc[ct]);
    atomicAdd(&ldsQ[ct * 16 + lr], sq[ct]);
  }
  __syncthreads();
  if (tid < N) {
    atomicAdd(&st_out[tid], ldsS[tid]);
    atomicAdd(&st_out[N + tid], ldsQ[tid]);
  }
}

// ---------------- dual-output MFMA matmul ----------------

__global__ __launch_bounds__(256) void mm2_mfma(const unsigned short* __restrict__ X,
                                                const unsigned short* __restrict__ Wbf,
                                                const float* __restrict__ B1,
                                                unsigned short* __restrict__ Y1,
                                                float* __restrict__ st1,
                                                const float* __restrict__ B2,
                                                unsigned short* __restrict__ Y2,
                                                float* __restrict__ st2,
                                                int M) {
  constexpr int K = 64, N1 = 64, N2 = 32, NT = 96, ROWS = 128;
  constexpr int LDX = K + 8, RT = 2, CT = 6, KV = K / 8;
  __shared__ alignas(16) unsigned short xl[ROWS * LDX];
  __shared__ alignas(16) unsigned short wl[NT * LDX];
  __shared__ float bl[NT];
  __shared__ float ldsS[NT], ldsQ[NT];

  int tid = threadIdx.x;
  for (int i = tid; i < NT * KV; i += 256) {
    int n = i / KV, kk = (i - n * KV) * 8;
    *reinterpret_cast<bfrag8*>(&wl[n * LDX + kk]) =
        *reinterpret_cast<const bfrag8*>(&Wbf[n * K + kk]);
  }
  for (int i = tid; i < N1; i += 256) bl[i] = B1[i];
  for (int i = tid; i < N2; i += 256) bl[N1 + i] = B2[i];
  if (tid < NT) { ldsS[tid] = 0.f; ldsQ[tid] = 0.f; }

  int lane = tid & 63;
  int wv   = tid >> 6;
  int lr   = lane & 15;
  int lk   = (lane >> 4) * 8;
  int lj4  = (lane >> 4) * 4;
  int rowbase = wv * 32;

  float sc[CT], sq[CT];
#pragma unroll
  for (int c = 0; c < CT; c++) { sc[c] = 0.f; sq[c] = 0.f; }

  int tiles = (M + ROWS - 1) / ROWS;
  for (int t = blockIdx.x; t < tiles; t += gridDim.x) {
    int r0 = t * ROWS;
    __syncthreads();
    for (int i = tid * 8; i < ROWS * K; i += 2048) {
      int r = i / K, c = i - r * K;
      int row = r0 + r;
      bfrag8 v = {0, 0, 0, 0, 0, 0, 0, 0};
      if (row < M) v = *reinterpret_cast<const bfrag8*>(X + (size_t)row * K + c);
      *reinterpret_cast<bfrag8*>(&xl[r * LDX + c]) = v;
    }
    __syncthreads();

    facc4 acc[RT][CT];
#pragma unroll
    for (int rt = 0; rt < RT; rt++)
#pragma unroll
      for (int ct = 0; ct < CT; ct++) acc[rt][ct] = (facc4){0.f, 0.f, 0.f, 0.f};

#pragma unroll
    for (int kt = 0; kt < K / 32; kt++) {
      bfrag8 a[RT], b[CT];
#pragma unroll
      for (int rt = 0; rt < RT; rt++)
        a[rt] = *reinterpret_cast<const bfrag8*>(&xl[(rowbase + rt * 16 + lr) * LDX + kt * 32 + lk]);
#pragma unroll
      for (int ct = 0; ct < CT; ct++)
        b[ct] = *reinterpret_cast<const bfrag8*>(&wl[(ct * 16 + lr) * LDX + kt * 32 + lk]);
#pragma unroll
      for (int rt = 0; rt < RT; rt++)
#pragma unroll
        for (int ct = 0; ct < CT; ct++)
          acc[rt][ct] = __builtin_amdgcn_mfma_f32_16x16x32_bf16(a[rt], b[ct], acc[rt][ct], 0, 0, 0);
    }

#pragma unroll
    for (int rt = 0; rt < RT; rt++) {
#pragma unroll
      for (int ct = 0; ct < CT; ct++) {
        int col = ct * 16 + lr;
        float bcol = bl[col];
#pragma unroll
        for (int j = 0; j < 4; j++) {
          int row = r0 + rowbase + rt * 16 + lj4 + j;
          if (row < M) {
            float v = acc[rt][ct][j] + bcol;
            if (col < N1) Y1[(size_t)row * N1 + col] = f2bf(v);
            else          Y2[(size_t)row * N2 + (col - N1)] = f2bf(v);
            sc[ct] += v; sq[ct] += v * v;
          }
        }
      }
    }
  }

  __syncthreads();
#pragma unroll
  for (int ct = 0; ct < CT; ct++) {
    atomicAdd(&ldsS[ct * 16 + lr], sc[ct]);
    atomicAdd(&ldsQ[ct * 16 + lr], sq[ct]);
  }
  __syncthreads();
  if (tid < NT) {
    if (tid < N1) {
      atomicAdd(&st1[tid], ldsS[tid]);
      atomicAdd(&st1[N1 + tid], ldsQ[tid]);
    } else {
      atomicAdd(&st2[tid - N1], ldsS[tid]);
      atomicAdd(&st2[N2 + (tid - N1)], ldsQ[tid]);
    }
  }
}

// ---------------- MFMA matmul on virtual concat h (K=128,N=64) ----------------

__global__ __launch_bounds__(256) void mmh_mfma(const unsigned short* __restrict__ x32,
                                                const unsigned short* __restrict__ ri,
                                                const unsigned short* __restrict__ li,
                                                const unsigned short* __restrict__ rli,
                                                const float* __restrict__ stx,
                                                const float* __restrict__ stri,
                                                const float* __restrict__ stli,
                                                const float* __restrict__ strli,
                                                const unsigned short* __restrict__ Wbf,
                                                const float* __restrict__ Bv,
                                                unsigned short* __restrict__ Y,
                                                float* __restrict__ st_out) {
  constexpr int K = 128, N = 64, ROWS = 128, LDX = K + 8, RT = 2, CT = 4, KV = K / 8;
  __shared__ alignas(16) unsigned short xl[ROWS * LDX];
  __shared__ alignas(16) unsigned short wl[N * LDX];
  __shared__ float bl[N];
  __shared__ float m4[4 * 32], s4[4 * 32];
  __shared__ float ldsS[N], ldsQ[N];

  int tid = threadIdx.x;
  for (int i = tid; i < N * KV; i += 256) {
    int n = i / KV, kk = (i - n * KV) * 8;
    *reinterpret_cast<bfrag8*>(&wl[n * LDX + kk]) =
        *reinterpret_cast<const bfrag8*>(&Wbf[n * K + kk]);
  }
  for (int i = tid; i < N; i += 256) bl[i] = Bv[i];
  if (tid < 128) {
    int s = tid >> 5, c = tid & 31;
    const float* st = (s == 0) ? stx : (s == 1) ? stri : (s == 2) ? stli : strli;
    float inv = (s == 0) ? (1.f / NTOT) : (s == 1) ? (1.f / NLEFT) : (1.f / NRIGHT);
    float m = st[c] * inv;
    float v = st[32 + c] * inv - m * m;
    m4[tid] = m;
    s4[tid] = rsqrtf(fmaxf(v, 0.f) + BNEPS);
  }
  if (tid < N) { ldsS[tid] = 0.f; ldsQ[tid] = 0.f; }

  int lane = tid & 63;
  int wv   = tid >> 6;
  int lr   = lane & 15;
  int lk   = (lane >> 4) * 8;
  int lj4  = (lane >> 4) * 4;
  int rowbase = wv * 32;

  float sc[CT], sq[CT];
#pragma unroll
  for (int c = 0; c < CT; c++) { sc[c] = 0.f; sq[c] = 0.f; }

  const int M = NTOT;
  int tiles = (M + ROWS - 1) / ROWS;
  for (int t = blockIdx.x; t < tiles; t += gridDim.x) {
    int r0 = t * ROWS;
    __syncthreads();
    for (int i = tid * 8; i < ROWS * K; i += 2048) {
      int r = i / K, c = i - r * K;
      int row = r0 + r;
      bfrag8 v = {0, 0, 0, 0, 0, 0, 0, 0};
      if (row < M) {
        int cb = c >> 5, cc = c & 31;
        const unsigned short* srcp;
        int set, srow;
        if (row < NLEFT) {
          if (cb == 1) { srcp = ri;  set = 1; srow = row; }
          else         { srcp = x32; set = 0; srow = row; }
        } else {
          int rr = row - NLEFT;
          if (cb <= 1)      { srcp = x32; set = 0; srow = row; }
          else if (cb == 2) { srcp = li;  set = 2; srow = rr; }
          else              { srcp = rli; set = 3; srow = rr; }
        }
        v = *reinterpret_cast<const bfrag8*>(srcp + (size_t)srow * 32 + cc);
        const float* mm_ = &m4[set * 32 + cc];
        const float* ss_ = &s4[set * 32 + cc];
#pragma unroll
        for (int j = 0; j < 8; j++) {
          float f = bf2f((unsigned short)v[j]);
          f = fmaxf((f - mm_[j]) * ss_[j], 0.f);
          v[j] = (short)f2bf(f);
        }
      }
      *reinterpret_cast<bfrag8*>(&xl[r * LDX + c]) = v;
    }
    __syncthreads();

    facc4 acc[RT][CT];
#pragma unroll
    for (int rt = 0; rt < RT; rt++)
#pragma unroll
      for (int ct = 0; ct < CT; ct++) acc[rt][ct] = (facc4){0.f, 0.f, 0.f, 0.f};

#pragma unroll
    for (int kt = 0; kt < K / 32; kt++) {
      bfrag8 a[RT], b[CT];
#pragma unroll
      for (int rt = 0; rt < RT; rt++)
        a[rt] = *reinterpret_cast<const bfrag8*>(&xl[(rowbase + rt * 16 + lr) * LDX + kt * 32 + lk]);
#pragma unroll
      for (int ct = 0; ct < CT; ct++)
        b[ct] = *reinterpret_cast<const bfrag8*>(&wl[(ct * 16 + lr) * LDX + kt * 32 + lk]);
#pragma unroll
      for (int rt = 0; rt < RT; rt++)
#pragma unroll
        for (int ct = 0; ct < CT; ct++)
          acc[rt][ct] = __builtin_amdgcn_mfma_f32_16x16x32_bf16(a[rt], b[ct], acc[rt][ct], 0, 0, 0);
    }

#pragma unroll
    for (int rt = 0; rt < RT; rt++) {
#pragma unroll
      for (int ct = 0; ct < CT; ct++) {
        int col = ct * 16 + lr;
        float bcol = bl[col];
#pragma unroll
        for (int j = 0; j < 4; j++) {
          int row = r0 + rowbase + rt * 16 + lj4 + j;
          if (row < M) {
            float v = acc[rt][ct][j] + bcol;
            Y[(size_t)row * N + col] = f2bf(v);
            sc[ct] += v; sq[ct] += v * v;
          }
        }
      }
    }
  }

  __syncthreads();
#pragma unroll
  for (int ct = 0; ct < CT; ct++) {
    atomicAdd(&ldsS[ct * 16 + lr], sc[ct]);
    atomicAdd(&ldsQ[ct * 16 + lr], sq[ct]);
  }
  __syncthreads();
  if (tid < N) {
    atomicAdd(&st_out[tid], ldsS[tid]);
    atomicAdd(&st_out[N + tid], ldsQ[tid]);
  }
}

// ---------------- final normalize + relu + residual add ----------------

__global__ __launch_bounds__(256) void norm_add_kernel(const unsigned short* __restrict__ X, int M,
                                                       const float* __restrict__ st,
                                                       float* __restrict__ D,
                                                       unsigned short* __restrict__ Dbf) {
  __shared__ float mean[64], scal[64];
  if (threadIdx.x < 64) {
    float m = st[threadIdx.x] / (float)M;
    float v = st[64 + threadIdx.x] / (float)M - m * m;
    mean[threadIdx.x] = m;
    scal[threadIdx.x] = rsqrtf(fmaxf(v, 0.f) + BNEPS);
  }
  __syncthreads();
  size_t ngrp = (size_t)M * 64 / 8;
  for (size_t i = (size_t)blockIdx.x * 256 + threadIdx.x; i < ngrp;
       i += (size_t)gridDim.x * 256) {
    size_t base = i * 8;
    int c = (int)(base & 63);
    bfrag8 xv = *reinterpret_cast<const bfrag8*>(&X[base]);
    float4 d0 = *reinterpret_cast<float4*>(&D[base]);
    float4 d1 = *reinterpret_cast<float4*>(&D[base + 4]);
    float o[8];
#pragma unroll
    for (int j = 0; j < 8; j++) {
      float y = (bf2f((unsigned short)xv[j]) - mean[c + j]) * scal[c + j];
      y = y > 0.f ? y : 0.f;
      float dv = (j < 4) ? (&d0.x)[j] : (&d1.x)[j - 4];
      o[j] = dv + y;
    }
    d0 = make_float4(o[0], o[1], o[2], o[3]);
    d1 = make_float4(o[4], o[5], o[6], o[7]);
    *reinterpret_cast<float4*>(&D[base])     = d0;
    *reinterpret_cast<float4*>(&D[base + 4]) = d1;
    bfrag8 pb;
#pragma unroll
    for (int j = 0; j < 8; j++) pb[j] = (short)f2bf(o[j]);
    *reinterpret_cast<bfrag8*>(&Dbf[base]) = pb;
  }
}

// ---------------- orchestration ----------------

static inline int tiles_of(int M, int R) { return (M + R - 1) / R; }
static inline int imin(int a, int b) { return a < b ? a : b; }

extern "C" void kernel_launch(void* const* d_in, const int* in_sizes, int n_in,
                              void* d_out, int out_size, void* d_ws, size_t ws_size,
                              hipStream_t stream) {
  const float* xs      = (const float*)d_in[0];
  const float* nn1_w1  = (const float*)d_in[1];
  const float* nn1_b1  = (const float*)d_in[2];
  const float* nn1_w2  = (const float*)d_in[3];
  const float* nn1_b2  = (const float*)d_in[4];
  const float* nn2_w1  = (const float*)d_in[5];
  const float* nn2_b1  = (const float*)d_in[6];
  const float* nn2_w2  = (const float*)d_in[7];
  const float* nn2_b2  = (const float*)d_in[8];
  const float* l1_w    = (const float*)d_in[9];
  const float* l1_b    = (const float*)d_in[10];
  const float* l2_w    = (const float*)d_in[11];
  const float* l2_b    = (const float*)d_in[12];
  const float* l3_w    = (const float*)d_in[13];
  const float* l3_b    = (const float*)d_in[14];
  const float* l4_w    = (const float*)d_in[15];
  const float* l4_b    = (const float*)d_in[16];
  const float* out_w1  = (const float*)d_in[17];
  const float* out_b1  = (const float*)d_in[18];
  const float* out_w2  = (const float*)d_in[19];
  const float* out_b2  = (const float*)d_in[20];
  const int*   src     = (const int*)d_in[21];
  const int*   dst     = (const int*)d_in[22];

  float* out = (float*)d_out;

  unsigned short* u     = (unsigned short*)d_ws;
  unsigned short* t1    = u;
  unsigned short* rin   = t1    + (size_t)NTOT * 64;
  unsigned short* x32   = rin   + (size_t)NLEFT * 64;
  unsigned short* ri32  = x32   + (size_t)NTOT * 32;
  unsigned short* li32  = ri32  + (size_t)NLEFT * 32;
  unsigned short* rli32 = li32  + (size_t)NRIGHT * 32;
  unsigned short* outbf = rli32 + (size_t)NRIGHT * 32;
  float* stats = (float*)(outbf + (size_t)NTOT * 64);
  int*   cntL  = (int*)(stats + 20 * 128);
  int*   cntR  = cntL + NLEFT;
  int*   oL    = cntR + NRIGHT;
  int*   oR    = oL + (NLEFT + 1);
  int*   curL  = oR + (NRIGHT + 1);
  int*   curR  = curL + NLEFT;
  int*   part  = curR + NRIGHT;
  int*   adjL  = part + 1024;
  int*   adjR  = adjL + NEDGE;
  unsigned short* wcvt = (unsigned short*)(adjR + NEDGE);       // 2*57344 ushorts
  int2*  binL  = (int2*)(wcvt + 2 * WC_PER_L);                  // NEDGE int2
  int2*  binR  = binL + NEDGE;
  int*   bcurL = (int*)(binR + NEDGE);                          // NBKT (+pad)
  int*   bcurR = bcurL + 256;

  dim3 B(256);
  const int NB1 = (NLEFT + 255) / 256;
  const float invL = 1.f / NLEFT, invT = 1.f / NTOT;
  const int tilesL = tiles_of(NLEFT, 32);
  const int GD = imin(tilesL, 768);

  init_kernel<<<2048, B, 0, stream>>>(xs, out, outbf, stats, 20 * 128, cntL, cntR, curL, curR);
  wconv_kernel<<<448, B, 0, stream>>>(l2_w, nn2_w1, l4_w, l3_w, nn2_w2, nn1_w1, l1_w,
                                      nn1_w2, out_w1, out_w2, wcvt);
  count_kernel<<<2048, B, 0, stream>>>(src, dst, cntL, cntR);
  scan1_kernel<<<NB1, B, 0, stream>>>(cntL, NLEFT, part);
  scan2_kernel<<<1, 1024, 0, stream>>>(part, NB1);
  scan3_kernel<<<NB1, B, 0, stream>>>(cntL, NLEFT, part, oL);
  scan1_kernel<<<NB1, B, 0, stream>>>(cntR, NRIGHT, part);
  scan2_kernel<<<1, 1024, 0, stream>>>(part, NB1);
  scan3_kernel<<<NB1, B, 0, stream>>>(cntR, NRIGHT, part, oR);
  // binned CSR fill: bucket offsets -> bin pairs -> L2-local scatter
  bucket_kernel<<<1, B, 0, stream>>>(cntL, cntR, bcurL, bcurR);
  bin_kernel<<<2048, B, 0, stream>>>(src, dst, bcurL, bcurR, binL, binR);
  scatter_kernel<<<NBKT, B, 0, stream>>>(binL, bcurL, oL, curL, adjL);
  scatter_kernel<<<NBKT, B, 0, stream>>>(binR, bcurR, oR, curR, adjR);

  for (int l = 0; l < 2; l++) {
    const float* p_nn1_b1 = nn1_b1 + (size_t)l * 64;
    const float* p_nn1_b2 = nn1_b2 + (size_t)l * 64;
    const float* p_nn2_b1 = nn2_b1 + (size_t)l * 64;
    const float* p_nn2_b2 = nn2_b2 + (size_t)l * 64;
    const float* p_l1_b   = l1_b + (size_t)l * 32;
    const float* p_l2_b   = l2_b + (size_t)l * 32;
    const float* p_l3_b   = l3_b + (size_t)l * 32;
    const float* p_l4_b   = l4_b + (size_t)l * 32;
    const float* p_out_b1 = out_b1 + (size_t)l * 64;
    const float* p_out_b2 = out_b2 + (size_t)l * 64;
    const unsigned short* wc = wcvt + (size_t)l * WC_PER_L;

    float* S = stats + (size_t)l * 10 * 128;
    auto ST = [&](int s) { return S + (size_t)s * 128; };

    // a+b+c1) gather right_info; ri=l2->s0; rin=nn2_w1->s1 (fused dual, persistent)
    gmm_mfma<32, 64, false><<<GD, 512, 0, stream>>>(
        outbf + (size_t)NLEFT * 64, oL, adjL, NLEFT, nullptr, 0.f,
        wc + WC_G1, p_l2_b, ri32, ST(0), p_nn2_b1, rin, ST(1));
    // c2) rin = nn2_w2(bnrelu(rin,s1)); s2
    mm_mfma<64, 64, 128, true><<<tiles_of(NLEFT, 128), B, 0, stream>>>(
        rin, wc + WC_NN2W2, p_nn2_b2, rin, NLEFT, ST(2), ST(1), invL);
    // f1+i) t1 = nn1_w1(outbf)->s4 ; x32 = l1(outbf)->s7
    mm2_mfma<<<tiles_of(NTOT, 128), B, 0, stream>>>(
        outbf, wc + WC_M2, p_nn1_b1, t1, ST(4), p_l1_b, x32, ST(7), NTOT);
    // f2) t1 = nn1_w2(bnrelu(t1,s4)); s5
    mm_mfma<64, 64, 128, true><<<tiles_of(NTOT, 128), B, 0, stream>>>(
        t1, wc + WC_NN1W2, p_nn1_b2, t1, NTOT, ST(5), ST(4), invT);
    // d+e & g+h fused: gather bnrelu(rin,s2) AND bnrelu(t1,s5) over adjR;
    //                  rli=l4->s3, li=l3->s6 (one adjacency pass)
    gmm2_mfma<<<GD, 512, 0, stream>>>(
        rin, ST(2), invL, t1, ST(5), invT, oR, adjR, NRIGHT,
        wc + WC_G2, p_l4_b, p_l3_b, rli32, ST(3), li32, ST(6));
    // j1) t1 = out_w1(h virtual concat); s8
    mmh_mfma<<<tiles_of(NTOT, 128), B, 0, stream>>>(
        x32, ri32, li32, rli32, ST(7), ST(0), ST(6), ST(3),
        wc + WC_OUTW1, p_out_b1, t1, ST(8));
    // j2) t1 = out_w2(bnrelu(t1,s8)); s9
    mm_mfma<64, 64, 128, true><<<tiles_of(NTOT, 128), B, 0, stream>>>(
        t1, wc + WC_OUTW2, p_out_b2, t1, NTOT, ST(9), ST(8), invT);
    // j3) out += relu(bn(t1,s9)); refresh bf16 mirror
    norm_add_kernel<<<2048, B, 0, stream>>>(t1, NTOT, ST(9), out, outbf);
  }
}

// Round 14
// 1146.954 us; speedup vs baseline: 1.6122x; 1.6122x over previous
//
#include <hip/hip_runtime.h>

#define NLEFT  100000
#define NRIGHT 100000
#define NTOT   200000
#define NEDGE  1000000
#define HD     64
#define BNEPS  1e-5f

typedef __attribute__((ext_vector_type(8))) short bfrag8;
typedef __attribute__((ext_vector_type(4))) float facc4;

__device__ inline unsigned short f2bf(float f) {
  unsigned u = __float_as_uint(f);
  u = u + 0x7fffu + ((u >> 16) & 1u);   // RNE
  return (unsigned short)(u >> 16);
}
__device__ inline float bf2f(unsigned short u) {
  return __uint_as_float((unsigned)u << 16);
}

// ---- converted-weight region layout (ushorts, per layer; see wconv_kernel) ----
#define WC_G1    0        // [96][192]  l2^T rows 0-31, nn2_w1^T rows 32-95
#define WC_G2    18432    // [32][192]  l4^T   (l3^T follows contiguously)
#define WC_G3    24576    // [32][192]  l3^T
#define WC_NN2W2 30720    // [64][64]
#define WC_M2    34816    // [96][64]   nn1_w1^T rows 0-63, l1^T rows 64-95
#define WC_NN1W2 40960    // [64][64]
#define WC_OUTW1 45056    // [64][128]
#define WC_OUTW2 53248    // [64][64]
#define WC_PER_L 57344

// ---------------- init ----------------

__global__ __launch_bounds__(256) void init_kernel(const float* __restrict__ xs,
                                                   float* __restrict__ out,
                                                   unsigned short* __restrict__ outbf,
                                                   float* __restrict__ st, int nst,
                                                   int* __restrict__ cl, int* __restrict__ cr,
                                                   int* __restrict__ curl, int* __restrict__ curr) {
  size_t ng = (size_t)NTOT * HD / 4;
  for (size_t i = (size_t)blockIdx.x * blockDim.x + threadIdx.x; i < ng;
       i += (size_t)gridDim.x * blockDim.x) {
    float4 v = reinterpret_cast<const float4*>(xs)[i];
    reinterpret_cast<float4*>(out)[i] = v;
    ushort4 p;
    p.x = f2bf(v.x); p.y = f2bf(v.y); p.z = f2bf(v.z); p.w = f2bf(v.w);
    reinterpret_cast<ushort4*>(outbf)[i] = p;
  }
  for (int i = blockIdx.x * blockDim.x + threadIdx.x; i < NLEFT;
       i += gridDim.x * blockDim.x) {
    cl[i] = 0; curl[i] = 0; cr[i] = 0; curr[i] = 0;
    if (i < nst) st[i] = 0.f;
  }
}

__global__ __launch_bounds__(256) void count_kernel(const int* __restrict__ src,
                                                    const int* __restrict__ dst,
                                                    int* __restrict__ cl, int* __restrict__ cr) {
  for (int e = blockIdx.x * blockDim.x + threadIdx.x; e < NEDGE;
       e += gridDim.x * blockDim.x) {
    atomicAdd(&cl[src[e]], 1);
    atomicAdd(&cr[dst[e]], 1);
  }
}

// ---------------- weight convert+transpose: fp32 [K][N] -> bf16 [N][K] ----------------

__global__ __launch_bounds__(256) void wconv_kernel(const float* __restrict__ l2w,
                                                    const float* __restrict__ nn2w1,
                                                    const float* __restrict__ l4w,
                                                    const float* __restrict__ l3w,
                                                    const float* __restrict__ nn2w2,
                                                    const float* __restrict__ nn1w1,
                                                    const float* __restrict__ l1w,
                                                    const float* __restrict__ nn1w2,
                                                    const float* __restrict__ outw1,
                                                    const float* __restrict__ outw2,
                                                    unsigned short* __restrict__ dst) {
  for (int idx = blockIdx.x * 256 + threadIdx.x; idx < 2 * WC_PER_L;
       idx += gridDim.x * 256) {
    int l = idx / WC_PER_L;
    int r = idx - l * WC_PER_L;
    const float* src; int N, n, k;
    if (r < WC_G2) {
      n = r / 192; k = r - n * 192;
      if (n < 32) { src = l2w + (size_t)l * 192 * 32; N = 32; }
      else        { src = nn2w1 + (size_t)l * 192 * 64; N = 64; n -= 32; }
    } else if (r < WC_G3) {
      int rr = r - WC_G2; n = rr / 192; k = rr - n * 192;
      src = l4w + (size_t)l * 192 * 32; N = 32;
    } else if (r < WC_NN2W2) {
      int rr = r - WC_G3; n = rr / 192; k = rr - n * 192;
      src = l3w + (size_t)l * 192 * 32; N = 32;
    } else if (r < WC_M2) {
      int rr = r - WC_NN2W2; n = rr / 64; k = rr - n * 64;
      src = nn2w2 + (size_t)l * 64 * 64; N = 64;
    } else if (r < WC_NN1W2) {
      int rr = r - WC_M2; n = rr / 64; k = rr - n * 64;
      if (n < 64) { src = nn1w1 + (size_t)l * 64 * 64; N = 64; }
      else        { src = l1w + (size_t)l * 64 * 32; N = 32; n -= 64; }
    } else if (r < WC_OUTW1) {
      int rr = r - WC_NN1W2; n = rr / 64; k = rr - n * 64;
      src = nn1w2 + (size_t)l * 64 * 64; N = 64;
    } else if (r < WC_OUTW2) {
      int rr = r - WC_OUTW1; n = rr / 128; k = rr - n * 128;
      src = outw1 + (size_t)l * 128 * 64; N = 64;
    } else {
      int rr = r - WC_OUTW2; n = rr / 64; k = rr - n * 64;
      src = outw2 + (size_t)l * 64 * 64; N = 64;
    }
    dst[idx] = f2bf(src[(size_t)k * N + n]);
  }
}

// ---------------- exclusive scan ----------------

__global__ __launch_bounds__(256) void scan1_kernel(const int* __restrict__ cnt, int n,
                                                    int* __restrict__ partial) {
  __shared__ int tmp[256];
  int i = blockIdx.x * 256 + threadIdx.x;
  tmp[threadIdx.x] = (i < n) ? cnt[i] : 0;
  __syncthreads();
  for (int s = 128; s > 0; s >>= 1) {
    if (threadIdx.x < s) tmp[threadIdx.x] += tmp[threadIdx.x + s];
    __syncthreads();
  }
  if (threadIdx.x == 0) partial[blockIdx.x] = tmp[0];
}

__global__ __launch_bounds__(1024) void scan2_kernel(int* __restrict__ partial, int nb) {
  __shared__ int tmp[1024];
  int t = threadIdx.x;
  int v = (t < nb) ? partial[t] : 0;
  tmp[t] = v;
  __syncthreads();
  for (int off = 1; off < 1024; off <<= 1) {
    int x = tmp[t];
    int add = (t >= off) ? tmp[t - off] : 0;
    __syncthreads();
    tmp[t] = x + add;
    __syncthreads();
  }
  if (t < nb) partial[t] = tmp[t] - v;
}

__global__ __launch_bounds__(256) void scan3_kernel(const int* __restrict__ cnt, int n,
                                                    const int* __restrict__ partial,
                                                    int* __restrict__ offs) {
  __shared__ int tmp[256];
  int t = threadIdx.x;
  int i = blockIdx.x * 256 + t;
  int v = (i < n) ? cnt[i] : 0;
  tmp[t] = v;
  __syncthreads();
  for (int off = 1; off < 256; off <<= 1) {
    int x = tmp[t];
    int add = (t >= off) ? tmp[t - off] : 0;
    __syncthreads();
    tmp[t] = x + add;
    __syncthreads();
  }
  if (i < n) offs[i] = tmp[t] - v + partial[blockIdx.x];
  if (i == 0) offs[n] = NEDGE;
}

// ---------------- CSR fill (single pass) ----------------

__global__ __launch_bounds__(256) void fill_kernel(const int* __restrict__ src,
                                                   const int* __restrict__ dst,
                                                   const int* __restrict__ oL,
                                                   const int* __restrict__ oR,
                                                   int* __restrict__ curL, int* __restrict__ curR,
                                                   int* __restrict__ adjL, int* __restrict__ adjR) {
  for (int e = blockIdx.x * blockDim.x + threadIdx.x; e < NEDGE;
       e += gridDim.x * blockDim.x) {
    int s = src[e], d = dst[e];
    int p = atomicAdd(&curL[s], 1);
    adjL[oL[s] + p] = d;
    int q = atomicAdd(&curR[d], 1);
    adjR[oR[d] + q] = s;
  }
}

// ---------------- fused gather + MFMA (persistent, pre-converted weights) ----------------

template <int N1, int N2, bool SRCNORM>
__global__ __launch_bounds__(512) void gmm_mfma(const unsigned short* __restrict__ mat,
                                                const int* __restrict__ offs,
                                                const int* __restrict__ adj,
                                                int nseg,
                                                const float* __restrict__ st_src, float inv_src,
                                                const unsigned short* __restrict__ Wbf,
                                                const float* __restrict__ B1,
                                                unsigned short* __restrict__ Y1,
                                                float* __restrict__ st1,
                                                const float* __restrict__ B2,
                                                unsigned short* __restrict__ Y2,
                                                float* __restrict__ st2) {
  constexpr int K    = 192;
  constexpr int LDX  = 200;
  constexpr int SEGS = 32;
  constexpr int NT   = N1 + N2;
  constexpr int CTT  = NT / 16;
  constexpr int CTW  = (CTT >= 6) ? 2 : 1;
  constexpr int NGRP = CTT / CTW;
  constexpr int NWM  = 2 * NGRP;
  __shared__ alignas(16) unsigned short xl[SEGS * LDX];
  __shared__ alignas(16) unsigned short wl[NT * LDX];
  __shared__ float bl[NT];
  __shared__ float ldsS[NT], ldsQ[NT];

  int tid = threadIdx.x;
  for (int i = tid; i < NT * 24; i += 512) {
    int n = i / 24, kk = (i - n * 24) * 8;
    *reinterpret_cast<bfrag8*>(&wl[n * LDX + kk]) =
        *reinterpret_cast<const bfrag8*>(&Wbf[n * 192 + kk]);
  }
  for (int i = tid; i < N1; i += 512) bl[i] = B1[i];
  if constexpr (N2 > 0)
    for (int i = tid; i < N2; i += 512) bl[N1 + i] = B2[i];
  if (tid < NT) { ldsS[tid] = 0.f; ldsQ[tid] = 0.f; }

  int wave = tid >> 6;
  int lane = tid & 63;
  int half = lane >> 5;
  int c0   = (lane & 31) * 2;

  float nm0 = 0.f, nm1 = 0.f, ns0 = 1.f, ns1 = 1.f;
  if (SRCNORM) {
    float m0 = st_src[c0] * inv_src, m1 = st_src[c0 + 1] * inv_src;
    float v0 = st_src[64 + c0] * inv_src - m0 * m0;
    float v1 = st_src[64 + c0 + 1] * inv_src - m1 * m1;
    nm0 = m0; nm1 = m1;
    ns0 = rsqrtf(fmaxf(v0, 0.f) + BNEPS);
    ns1 = rsqrtf(fmaxf(v1, 0.f) + BNEPS);
  }

  int lr  = lane & 15;
  int lk  = (lane >> 4) * 8;
  int lj4 = (lane >> 4) * 4;
  int rowtile = wave & 1;
  int colgrp  = wave >> 1;
  int rowbase = rowtile * 16;

  float sacc[CTW], qacc[CTW];
#pragma unroll
  for (int ct = 0; ct < CTW; ct++) { sacc[ct] = 0.f; qacc[ct] = 0.f; }

  int tiles = (nseg + SEGS - 1) / SEGS;
  for (int t = blockIdx.x; t < tiles; t += gridDim.x) {
    __syncthreads();
    int segbase = t * SEGS + wave * 4;
    for (int s = 0; s < 4; s++) {
      int seg = segbase + s;
      int row = wave * 4 + s;
      float s0 = 0.f, s1 = 0.f, m0 = -INFINITY, m1 = -INFINITY;
      int cdeg = 0;
      if (seg < nseg) {
        int b = offs[seg], e = offs[seg + 1];
        cdeg = e - b;
        for (int jb = b + half; jb < e; jb += 16) {
          unsigned pk[8];
#pragma unroll
          for (int u = 0; u < 8; u++) {
            int j = jb + 2 * u;
            pk[u] = 0;
            if (j < e) {
              int g = adj[j];
              pk[u] = *reinterpret_cast<const unsigned*>(&mat[(size_t)g * HD + c0]);
            }
          }
#pragma unroll
          for (int u = 0; u < 8; u++) {
            int j = jb + 2 * u;
            if (j < e) {
              float v0 = __uint_as_float(pk[u] << 16);
              float v1 = __uint_as_float(pk[u] & 0xffff0000u);
              if (SRCNORM) {
                v0 = fmaxf((v0 - nm0) * ns0, 0.f);
                v1 = fmaxf((v1 - nm1) * ns1, 0.f);
              }
              s0 += v0; s1 += v1;
              m0 = fmaxf(m0, v0); m1 = fmaxf(m1, v1);
            }
          }
        }
        s0 += __shfl_xor(s0, 32);
        s1 += __shfl_xor(s1, 32);
        m0 = fmaxf(m0, __shfl_xor(m0, 32));
        m1 = fmaxf(m1, __shfl_xor(m1, 32));
      }
      float inv = 1.f / fmaxf((float)cdeg, 1.f);
      if (cdeg == 0) { m0 = 0.f; m1 = 0.f; s0 = 0.f; s1 = 0.f; }
      if (half == 0) {
        unsigned sp = (unsigned)f2bf(s0) | ((unsigned)f2bf(s1) << 16);
        unsigned mp = (unsigned)f2bf(m0) | ((unsigned)f2bf(m1) << 16);
        *reinterpret_cast<unsigned*>(&xl[row * LDX + c0])       = sp;
        *reinterpret_cast<unsigned*>(&xl[row * LDX + 128 + c0]) = mp;
      } else {
        unsigned ap = (unsigned)f2bf(s0 * inv) | ((unsigned)f2bf(s1 * inv) << 16);
        *reinterpret_cast<unsigned*>(&xl[row * LDX + 64 + c0]) = ap;
      }
    }
    __syncthreads();

    if (wave < NWM) {
      facc4 acc[CTW];
#pragma unroll
      for (int ct = 0; ct < CTW; ct++) acc[ct] = (facc4){0.f, 0.f, 0.f, 0.f};
#pragma unroll
      for (int kt = 0; kt < K / 32; kt++) {
        bfrag8 a = *reinterpret_cast<const bfrag8*>(&xl[(rowbase + lr) * LDX + kt * 32 + lk]);
#pragma unroll
        for (int ct = 0; ct < CTW; ct++) {
          bfrag8 b = *reinterpret_cast<const bfrag8*>(
              &wl[((colgrp * CTW + ct) * 16 + lr) * LDX + kt * 32 + lk]);
          acc[ct] = __builtin_amdgcn_mfma_f32_16x16x32_bf16(a, b, acc[ct], 0, 0, 0);
        }
      }
#pragma unroll
      for (int ct = 0; ct < CTW; ct++) {
        int col = (colgrp * CTW + ct) * 16 + lr;
        float bias = bl[col];
#pragma unroll
        for (int j = 0; j < 4; j++) {
          int grow = t * SEGS + rowbase + lj4 + j;
          if (grow < nseg) {
            float v = acc[ct][j] + bias;
            if (col < N1) Y1[(size_t)grow * N1 + col] = f2bf(v);
            else          Y2[(size_t)grow * N2 + (col - N1)] = f2bf(v);
            sacc[ct] += v; qacc[ct] += v * v;
          }
        }
      }
    }
  }

  __syncthreads();
  if (wave < NWM) {
#pragma unroll
    for (int ct = 0; ct < CTW; ct++) {
      int col = (colgrp * CTW + ct) * 16 + lr;
      atomicAdd(&ldsS[col], sacc[ct]);
      atomicAdd(&ldsQ[col], qacc[ct]);
    }
  }
  __syncthreads();
  if (tid < NT) {
    if (tid < N1) {
      atomicAdd(&st1[tid], ldsS[tid]);
      atomicAdd(&st1[N1 + tid], ldsQ[tid]);
    } else {
      atomicAdd(&st2[tid - N1], ldsS[tid]);
      atomicAdd(&st2[N2 + (tid - N1)], ldsQ[tid]);
    }
  }
}

// ---------------- dual-SOURCE fused gather + MFMA: two mats, one adjacency ----------------

__global__ __launch_bounds__(512) void gmm2_mfma(const unsigned short* __restrict__ matA,
                                                 const float* __restrict__ stA, float invA,
                                                 const unsigned short* __restrict__ matB,
                                                 const float* __restrict__ stB, float invB,
                                                 const int* __restrict__ offs,
                                                 const int* __restrict__ adj,
                                                 int nseg,
                                                 const unsigned short* __restrict__ Wbf,
                                                 const float* __restrict__ BA,
                                                 const float* __restrict__ BB,
                                                 unsigned short* __restrict__ YA,
                                                 float* __restrict__ st1,
                                                 unsigned short* __restrict__ YB,
                                                 float* __restrict__ st2) {
  constexpr int K = 192, LDX = 200, SEGS = 32;
  __shared__ alignas(16) unsigned short xlA[SEGS * LDX];
  __shared__ alignas(16) unsigned short xlB[SEGS * LDX];
  __shared__ alignas(16) unsigned short wl[64 * LDX];
  __shared__ float bl[64];
  __shared__ float ldsS[64], ldsQ[64];

  int tid = threadIdx.x;
  for (int i = tid; i < 64 * 24; i += 512) {
    int n = i / 24, kk = (i - n * 24) * 8;
    *reinterpret_cast<bfrag8*>(&wl[n * LDX + kk]) =
        *reinterpret_cast<const bfrag8*>(&Wbf[n * 192 + kk]);
  }
  if (tid < 32) bl[tid] = BA[tid];
  else if (tid < 64) bl[tid] = BB[tid - 32];
  if (tid < 64) { ldsS[tid] = 0.f; ldsQ[tid] = 0.f; }

  int wave = tid >> 6;
  int lane = tid & 63;
  int half = lane >> 5;
  int c0   = (lane & 31) * 2;

  float nmA0, nmA1, nsA0, nsA1, nmB0, nmB1, nsB0, nsB1;
  {
    float m0 = stA[c0] * invA, m1 = stA[c0 + 1] * invA;
    float v0 = stA[64 + c0] * invA - m0 * m0;
    float v1 = stA[64 + c0 + 1] * invA - m1 * m1;
    nmA0 = m0; nmA1 = m1;
    nsA0 = rsqrtf(fmaxf(v0, 0.f) + BNEPS);
    nsA1 = rsqrtf(fmaxf(v1, 0.f) + BNEPS);
    m0 = stB[c0] * invB; m1 = stB[c0 + 1] * invB;
    v0 = stB[64 + c0] * invB - m0 * m0;
    v1 = stB[64 + c0 + 1] * invB - m1 * m1;
    nmB0 = m0; nmB1 = m1;
    nsB0 = rsqrtf(fmaxf(v0, 0.f) + BNEPS);
    nsB1 = rsqrtf(fmaxf(v1, 0.f) + BNEPS);
  }

  int lr  = lane & 15;
  int lk  = (lane >> 4) * 8;
  int lj4 = (lane >> 4) * 4;
  int grp     = wave >> 2;
  int rowtile = wave & 1;
  int ctile   = (wave >> 1) & 1;
  int rowbase = rowtile * 16;

  float sacc = 0.f, qacc = 0.f;

  int tiles = (nseg + SEGS - 1) / SEGS;
  for (int t = blockIdx.x; t < tiles; t += gridDim.x) {
    __syncthreads();
    int segbase = t * SEGS + wave * 4;
    for (int s = 0; s < 4; s++) {
      int seg = segbase + s;
      int row = wave * 4 + s;
      float sA0 = 0.f, sA1 = 0.f, mA0 = -INFINITY, mA1 = -INFINITY;
      float sB0 = 0.f, sB1 = 0.f, mB0 = -INFINITY, mB1 = -INFINITY;
      int cdeg = 0;
      if (seg < nseg) {
        int b = offs[seg], e = offs[seg + 1];
        cdeg = e - b;
        for (int jb = b + half; jb < e; jb += 16) {
          unsigned pkA[8], pkB[8];
#pragma unroll
          for (int u = 0; u < 8; u++) {
            int j = jb + 2 * u;
            pkA[u] = 0; pkB[u] = 0;
            if (j < e) {
              int g = adj[j];
              pkA[u] = *reinterpret_cast<const unsigned*>(&matA[(size_t)g * HD + c0]);
              pkB[u] = *reinterpret_cast<const unsigned*>(&matB[(size_t)g * HD + c0]);
            }
          }
#pragma unroll
          for (int u = 0; u < 8; u++) {
            int j = jb + 2 * u;
            if (j < e) {
              float a0 = fmaxf((__uint_as_float(pkA[u] << 16) - nmA0) * nsA0, 0.f);
              float a1 = fmaxf((__uint_as_float(pkA[u] & 0xffff0000u) - nmA1) * nsA1, 0.f);
              float b0 = fmaxf((__uint_as_float(pkB[u] << 16) - nmB0) * nsB0, 0.f);
              float b1 = fmaxf((__uint_as_float(pkB[u] & 0xffff0000u) - nmB1) * nsB1, 0.f);
              sA0 += a0; sA1 += a1; mA0 = fmaxf(mA0, a0); mA1 = fmaxf(mA1, a1);
              sB0 += b0; sB1 += b1; mB0 = fmaxf(mB0, b0); mB1 = fmaxf(mB1, b1);
            }
          }
        }
        sA0 += __shfl_xor(sA0, 32);
        sA1 += __shfl_xor(sA1, 32);
        mA0 = fmaxf(mA0, __shfl_xor(mA0, 32));
        mA1 = fmaxf(mA1, __shfl_xor(mA1, 32));
        sB0 += __shfl_xor(sB0, 32);
        sB1 += __shfl_xor(sB1, 32);
        mB0 = fmaxf(mB0, __shfl_xor(mB0, 32));
        mB1 = fmaxf(mB1, __shfl_xor(mB1, 32));
      }
      float inv = 1.f / fmaxf((float)cdeg, 1.f);
      if (cdeg == 0) { mA0 = 0.f; mA1 = 0.f; mB0 = 0.f; mB1 = 0.f;
                       sA0 = 0.f; sA1 = 0.f; sB0 = 0.f; sB1 = 0.f; }
      if (half == 0) {
        *reinterpret_cast<unsigned*>(&xlA[row * LDX + c0]) =
            (unsigned)f2bf(sA0) | ((unsigned)f2bf(sA1) << 16);
        *reinterpret_cast<unsigned*>(&xlA[row * LDX + 128 + c0]) =
            (unsigned)f2bf(mA0) | ((unsigned)f2bf(mA1) << 16);
        *reinterpret_cast<unsigned*>(&xlB[row * LDX + c0]) =
            (unsigned)f2bf(sB0) | ((unsigned)f2bf(sB1) << 16);
        *reinterpret_cast<unsigned*>(&xlB[row * LDX + 128 + c0]) =
            (unsigned)f2bf(mB0) | ((unsigned)f2bf(mB1) << 16);
      } else {
        *reinterpret_cast<unsigned*>(&xlA[row * LDX + 64 + c0]) =
            (unsigned)f2bf(sA0 * inv) | ((unsigned)f2bf(sA1 * inv) << 16);
        *reinterpret_cast<unsigned*>(&xlB[row * LDX + 64 + c0]) =
            (unsigned)f2bf(sB0 * inv) | ((unsigned)f2bf(sB1 * inv) << 16);
      }
    }
    __syncthreads();

    {
      const unsigned short* xl = grp ? xlB : xlA;
      facc4 acc = (facc4){0.f, 0.f, 0.f, 0.f};
#pragma unroll
      for (int kt = 0; kt < K / 32; kt++) {
        bfrag8 a = *reinterpret_cast<const bfrag8*>(&xl[(rowbase + lr) * LDX + kt * 32 + lk]);
        bfrag8 b = *reinterpret_cast<const bfrag8*>(
            &wl[(grp * 32 + ctile * 16 + lr) * LDX + kt * 32 + lk]);
        acc = __builtin_amdgcn_mfma_f32_16x16x32_bf16(a, b, acc, 0, 0, 0);
      }
      int col = ctile * 16 + lr;
      float bias = bl[grp * 32 + col];
      unsigned short* Y = grp ? YB : YA;
#pragma unroll
      for (int j = 0; j < 4; j++) {
        int grow = t * SEGS + rowbase + lj4 + j;
        if (grow < nseg) {
          float v = acc[j] + bias;
          Y[(size_t)grow * 32 + col] = f2bf(v);
          sacc += v; qacc += v * v;
        }
      }
    }
  }

  __syncthreads();
  atomicAdd(&ldsS[grp * 32 + ctile * 16 + lr], sacc);
  atomicAdd(&ldsQ[grp * 32 + ctile * 16 + lr], qacc);
  __syncthreads();
  if (tid < 64) {
    if (tid < 32) {
      atomicAdd(&st1[tid], ldsS[tid]);
      atomicAdd(&st1[32 + tid], ldsQ[tid]);
    } else {
      atomicAdd(&st2[tid - 32], ldsS[tid]);
      atomicAdd(&st2[32 + (tid - 32)], ldsQ[tid]);
    }
  }
}

// ---------------- MFMA matmul (pre-converted weights) ----------------

template <int K, int N, int ROWS, bool NIN>
__global__ __launch_bounds__(256) void mm_mfma(const unsigned short* __restrict__ X,
                                               const unsigned short* __restrict__ Wbf,
                                               const float* __restrict__ Bv,
                                               unsigned short* __restrict__ Y, int M,
                                               float* __restrict__ st_out,
                                               const float* __restrict__ st_in, float inv_m) {
  constexpr int LDX = K + 8;
  constexpr int RT  = ROWS / 64;
  constexpr int CT  = N / 16;
  constexpr int KV  = K / 8;
  __shared__ alignas(16) unsigned short xl[ROWS * LDX];
  __shared__ alignas(16) unsigned short wl[N * LDX];
  __shared__ float bl[N];
  __shared__ float nmean[K], nscal[K];
  __shared__ float ldsS[N], ldsQ[N];

  int tid = threadIdx.x;
  for (int i = tid; i < N * KV; i += 256) {
    int n = i / KV, kk = (i - n * KV) * 8;
    *reinterpret_cast<bfrag8*>(&wl[n * LDX + kk]) =
        *reinterpret_cast<const bfrag8*>(&Wbf[n * K + kk]);
  }
  for (int i = tid; i < N; i += 256) bl[i] = Bv[i];
  if (NIN) {
    for (int i = tid; i < K; i += 256) {
      float m = st_in[i] * inv_m;
      float v = st_in[K + i] * inv_m - m * m;
      nmean[i] = m;
      nscal[i] = rsqrtf(fmaxf(v, 0.f) + BNEPS);
    }
  }
  if (tid < N) { ldsS[tid] = 0.f; ldsQ[tid] = 0.f; }

  int lane = tid & 63;
  int wv   = tid >> 6;
  int lr   = lane & 15;
  int lk   = (lane >> 4) * 8;
  int lj4  = (lane >> 4) * 4;
  int rowbase = wv * (RT * 16);

  float sc[CT], sq[CT];
#pragma unroll
  for (int c = 0; c < CT; c++) { sc[c] = 0.f; sq[c] = 0.f; }

  int tiles = (M + ROWS - 1) / ROWS;
  for (int t = blockIdx.x; t < tiles; t += gridDim.x) {
    int r0 = t * ROWS;
    __syncthreads();
    for (int i = tid * 8; i < ROWS * K; i += 2048) {
      int r = i / K, c = i - r * K;
      int row = r0 + r;
      bfrag8 v = {0, 0, 0, 0, 0, 0, 0, 0};
      if (row < M) {
        v = *reinterpret_cast<const bfrag8*>(X + (size_t)row * K + c);
        if (NIN) {
#pragma unroll
          for (int j = 0; j < 8; j++) {
            float f = bf2f((unsigned short)v[j]);
            f = fmaxf((f - nmean[c + j]) * nscal[c + j], 0.f);
            v[j] = (short)f2bf(f);
          }
        }
      }
      *reinterpret_cast<bfrag8*>(&xl[r * LDX + c]) = v;
    }
    __syncthreads();

    facc4 acc[RT][CT];
#pragma unroll
    for (int rt = 0; rt < RT; rt++)
#pragma unroll
      for (int ct = 0; ct < CT; ct++) acc[rt][ct] = (facc4){0.f, 0.f, 0.f, 0.f};

#pragma unroll
    for (int kt = 0; kt < K / 32; kt++) {
      bfrag8 a[RT], b[CT];
#pragma unroll
      for (int rt = 0; rt < RT; rt++)
        a[rt] = *reinterpret_cast<const bfrag8*>(&xl[(rowbase + rt * 16 + lr) * LDX + kt * 32 + lk]);
#pragma unroll
      for (int ct = 0; ct < CT; ct++)
        b[ct] = *reinterpret_cast<const bfrag8*>(&wl[(ct * 16 + lr) * LDX + kt * 32 + lk]);
#pragma unroll
      for (int rt = 0; rt < RT; rt++)
#pragma unroll
        for (int ct = 0; ct < CT; ct++)
          acc[rt][ct] = __builtin_amdgcn_mfma_f32_16x16x32_bf16(a[rt], b[ct], acc[rt][ct], 0, 0, 0);
    }

#pragma unroll
    for (int rt = 0; rt < RT; rt++) {
#pragma unroll
      for (int ct = 0; ct < CT; ct++) {
        int col = ct * 16 + lr;
        float bcol = bl[col];
#pragma unroll
        for (int j = 0; j < 4; j++) {
          int row = r0 + rowbase + rt * 16 + lj4 + j;
          if (row < M) {
            float v = acc[rt][ct][j] + bcol;
            Y[(size_t)row * N + col] = f2bf(v);
            sc[ct] += v; sq[ct] += v * v;
          }
        }
      }
    }
  }

  __syncthreads();
#pragma unroll
  for (int ct = 0; ct < CT; ct++) {
    atomicAdd(&ldsS[ct * 16 + lr], sc[ct]);
    atomicAdd(&ldsQ[ct * 16 + lr], sq[ct]);
  }
  __syncthreads();
  if (tid < N) {
    atomicAdd(&st_out[tid], ldsS[tid]);
    atomicAdd(&st_out[N + tid], ldsQ[tid]);
  }
}

// ---------------- dual-output MFMA matmul ----------------

__global__ __launch_bounds__(256) void mm2_mfma(const unsigned short* __restrict__ X,
                                                const unsigned short* __restrict__ Wbf,
                                                const float* __restrict__ B1,
                                                unsigned short* __restrict__ Y1,
                                                float* __restrict__ st1,
                                                const float* __restrict__ B2,
                                                unsigned short* __restrict__ Y2,
                                                float* __restrict__ st2,
                                                int M) {
  constexpr int K = 64, N1 = 64, N2 = 32, NT = 96, ROWS = 128;
  constexpr int LDX = K + 8, RT = 2, CT = 6, KV = K / 8;
  __shared__ alignas(16) unsigned short xl[ROWS * LDX];
  __shared__ alignas(16) unsigned short wl[NT * LDX];
  __shared__ float bl[NT];
  __shared__ float ldsS[NT], ldsQ[NT];

  int tid = threadIdx.x;
  for (int i = tid; i < NT * KV; i += 256) {
    int n = i / KV, kk = (i - n * KV) * 8;
    *reinterpret_cast<bfrag8*>(&wl[n * LDX + kk]) =
        *reinterpret_cast<const bfrag8*>(&Wbf[n * K + kk]);
  }
  for (int i = tid; i < N1; i += 256) bl[i] = B1[i];
  for (int i = tid; i < N2; i += 256) bl[N1 + i] = B2[i];
  if (tid < NT) { ldsS[tid] = 0.f; ldsQ[tid] = 0.f; }

  int lane = tid & 63;
  int wv   = tid >> 6;
  int lr   = lane & 15;
  int lk   = (lane >> 4) * 8;
  int lj4  = (lane >> 4) * 4;
  int rowbase = wv * 32;

  float sc[CT], sq[CT];
#pragma unroll
  for (int c = 0; c < CT; c++) { sc[c] = 0.f; sq[c] = 0.f; }

  int tiles = (M + ROWS - 1) / ROWS;
  for (int t = blockIdx.x; t < tiles; t += gridDim.x) {
    int r0 = t * ROWS;
    __syncthreads();
    for (int i = tid * 8; i < ROWS * K; i += 2048) {
      int r = i / K, c = i - r * K;
      int row = r0 + r;
      bfrag8 v = {0, 0, 0, 0, 0, 0, 0, 0};
      if (row < M) v = *reinterpret_cast<const bfrag8*>(X + (size_t)row * K + c);
      *reinterpret_cast<bfrag8*>(&xl[r * LDX + c]) = v;
    }
    __syncthreads();

    facc4 acc[RT][CT];
#pragma unroll
    for (int rt = 0; rt < RT; rt++)
#pragma unroll
      for (int ct = 0; ct < CT; ct++) acc[rt][ct] = (facc4){0.f, 0.f, 0.f, 0.f};

#pragma unroll
    for (int kt = 0; kt < K / 32; kt++) {
      bfrag8 a[RT], b[CT];
#pragma unroll
      for (int rt = 0; rt < RT; rt++)
        a[rt] = *reinterpret_cast<const bfrag8*>(&xl[(rowbase + rt * 16 + lr) * LDX + kt * 32 + lk]);
#pragma unroll
      for (int ct = 0; ct < CT; ct++)
        b[ct] = *reinterpret_cast<const bfrag8*>(&wl[(ct * 16 + lr) * LDX + kt * 32 + lk]);
#pragma unroll
      for (int rt = 0; rt < RT; rt++)
#pragma unroll
        for (int ct = 0; ct < CT; ct++)
          acc[rt][ct] = __builtin_amdgcn_mfma_f32_16x16x32_bf16(a[rt], b[ct], acc[rt][ct], 0, 0, 0);
    }

#pragma unroll
    for (int rt = 0; rt < RT; rt++) {
#pragma unroll
      for (int ct = 0; ct < CT; ct++) {
        int col = ct * 16 + lr;
        float bcol = bl[col];
#pragma unroll
        for (int j = 0; j < 4; j++) {
          int row = r0 + rowbase + rt * 16 + lj4 + j;
          if (row < M) {
            float v = acc[rt][ct][j] + bcol;
            if (col < N1) Y1[(size_t)row * N1 + col] = f2bf(v);
            else          Y2[(size_t)row * N2 + (col - N1)] = f2bf(v);
            sc[ct] += v; sq[ct] += v * v;
          }
        }
      }
    }
  }

  __syncthreads();
#pragma unroll
  for (int ct = 0; ct < CT; ct++) {
    atomicAdd(&ldsS[ct * 16 + lr], sc[ct]);
    atomicAdd(&ldsQ[ct * 16 + lr], sq[ct]);
  }
  __syncthreads();
  if (tid < NT) {
    if (tid < N1) {
      atomicAdd(&st1[tid], ldsS[tid]);
      atomicAdd(&st1[N1 + tid], ldsQ[tid]);
    } else {
      atomicAdd(&st2[tid - N1], ldsS[tid]);
      atomicAdd(&st2[N2 + (tid - N1)], ldsQ[tid]);
    }
  }
}

// ---------------- MFMA matmul on virtual concat h (K=128,N=64) ----------------

__global__ __launch_bounds__(256) void mmh_mfma(const unsigned short* __restrict__ x32,
                                                const unsigned short* __restrict__ ri,
                                                const unsigned short* __restrict__ li,
                                                const unsigned short* __restrict__ rli,
                                                const float* __restrict__ stx,
                                                const float* __restrict__ stri,
                                                const float* __restrict__ stli,
                                                const float* __restrict__ strli,
                                                const unsigned short* __restrict__ Wbf,
                                                const float* __restrict__ Bv,
                                                unsigned short* __restrict__ Y,
                                                float* __restrict__ st_out) {
  constexpr int K = 128, N = 64, ROWS = 128, LDX = K + 8, RT = 2, CT = 4, KV = K / 8;
  __shared__ alignas(16) unsigned short xl[ROWS * LDX];
  __shared__ alignas(16) unsigned short wl[N * LDX];
  __shared__ float bl[N];
  __shared__ float m4[4 * 32], s4[4 * 32];
  __shared__ float ldsS[N], ldsQ[N];

  int tid = threadIdx.x;
  for (int i = tid; i < N * KV; i += 256) {
    int n = i / KV, kk = (i - n * KV) * 8;
    *reinterpret_cast<bfrag8*>(&wl[n * LDX + kk]) =
        *reinterpret_cast<const bfrag8*>(&Wbf[n * K + kk]);
  }
  for (int i = tid; i < N; i += 256) bl[i] = Bv[i];
  if (tid < 128) {
    int s = tid >> 5, c = tid & 31;
    const float* st = (s == 0) ? stx : (s == 1) ? stri : (s == 2) ? stli : strli;
    float inv = (s == 0) ? (1.f / NTOT) : (s == 1) ? (1.f / NLEFT) : (1.f / NRIGHT);
    float m = st[c] * inv;
    float v = st[32 + c] * inv - m * m;
    m4[tid] = m;
    s4[tid] = rsqrtf(fmaxf(v, 0.f) + BNEPS);
  }
  if (tid < N) { ldsS[tid] = 0.f; ldsQ[tid] = 0.f; }

  int lane = tid & 63;
  int wv   = tid >> 6;
  int lr   = lane & 15;
  int lk   = (lane >> 4) * 8;
  int lj4  = (lane >> 4) * 4;
  int rowbase = wv * 32;

  float sc[CT], sq[CT];
#pragma unroll
  for (int c = 0; c < CT; c++) { sc[c] = 0.f; sq[c] = 0.f; }

  const int M = NTOT;
  int tiles = (M + ROWS - 1) / ROWS;
  for (int t = blockIdx.x; t < tiles; t += gridDim.x) {
    int r0 = t * ROWS;
    __syncthreads();
    for (int i = tid * 8; i < ROWS * K; i += 2048) {
      int r = i / K, c = i - r * K;
      int row = r0 + r;
      bfrag8 v = {0, 0, 0, 0, 0, 0, 0, 0};
      if (row < M) {
        int cb = c >> 5, cc = c & 31;
        const unsigned short* srcp;
        int set, srow;
        if (row < NLEFT) {
          if (cb == 1) { srcp = ri;  set = 1; srow = row; }
          else         { srcp = x32; set = 0; srow = row; }
        } else {
          int rr = row - NLEFT;
          if (cb <= 1)      { srcp = x32; set = 0; srow = row; }
          else if (cb == 2) { srcp = li;  set = 2; srow = rr; }
          else              { srcp = rli; set = 3; srow = rr; }
        }
        v = *reinterpret_cast<const bfrag8*>(srcp + (size_t)srow * 32 + cc);
        const float* mm_ = &m4[set * 32 + cc];
        const float* ss_ = &s4[set * 32 + cc];
#pragma unroll
        for (int j = 0; j < 8; j++) {
          float f = bf2f((unsigned short)v[j]);
          f = fmaxf((f - mm_[j]) * ss_[j], 0.f);
          v[j] = (short)f2bf(f);
        }
      }
      *reinterpret_cast<bfrag8*>(&xl[r * LDX + c]) = v;
    }
    __syncthreads();

    facc4 acc[RT][CT];
#pragma unroll
    for (int rt = 0; rt < RT; rt++)
#pragma unroll
      for (int ct = 0; ct < CT; ct++) acc[rt][ct] = (facc4){0.f, 0.f, 0.f, 0.f};

#pragma unroll
    for (int kt = 0; kt < K / 32; kt++) {
      bfrag8 a[RT], b[CT];
#pragma unroll
      for (int rt = 0; rt < RT; rt++)
        a[rt] = *reinterpret_cast<const bfrag8*>(&xl[(rowbase + rt * 16 + lr) * LDX + kt * 32 + lk]);
#pragma unroll
      for (int ct = 0; ct < CT; ct++)
        b[ct] = *reinterpret_cast<const bfrag8*>(&wl[(ct * 16 + lr) * LDX + kt * 32 + lk]);
#pragma unroll
      for (int rt = 0; rt < RT; rt++)
#pragma unroll
        for (int ct = 0; ct < CT; ct++)
          acc[rt][ct] = __builtin_amdgcn_mfma_f32_16x16x32_bf16(a[rt], b[ct], acc[rt][ct], 0, 0, 0);
    }

#pragma unroll
    for (int rt = 0; rt < RT; rt++) {
#pragma unroll
      for (int ct = 0; ct < CT; ct++) {
        int col = ct * 16 + lr;
        float bcol = bl[col];
#pragma unroll
        for (int j = 0; j < 4; j++) {
          int row = r0 + rowbase + rt * 16 + lj4 + j;
          if (row < M) {
            float v = acc[rt][ct][j] + bcol;
            Y[(size_t)row * N + col] = f2bf(v);
            sc[ct] += v; sq[ct] += v * v;
          }
        }
      }
    }
  }

  __syncthreads();
#pragma unroll
  for (int ct = 0; ct < CT; ct++) {
    atomicAdd(&ldsS[ct * 16 + lr], sc[ct]);
    atomicAdd(&ldsQ[ct * 16 + lr], sq[ct]);
  }
  __syncthreads();
  if (tid < N) {
    atomicAdd(&st_out[tid], ldsS[tid]);
    atomicAdd(&st_out[N + tid], ldsQ[tid]);
  }
}

// ---------------- final normalize + relu + residual add ----------------

__global__ __launch_bounds__(256) void norm_add_kernel(const unsigned short* __restrict__ X, int M,
                                                       const float* __restrict__ st,
                                                       float* __restrict__ D,
                                                       unsigned short* __restrict__ Dbf) {
  __shared__ float mean[64], scal[64];
  if (threadIdx.x < 64) {
    float m = st[threadIdx.x] / (float)M;
    float v = st[64 + threadIdx.x] / (float)M - m * m;
    mean[threadIdx.x] = m;
    scal[threadIdx.x] = rsqrtf(fmaxf(v, 0.f) + BNEPS);
  }
  __syncthreads();
  size_t ngrp = (size_t)M * 64 / 8;
  for (size_t i = (size_t)blockIdx.x * 256 + threadIdx.x; i < ngrp;
       i += (size_t)gridDim.x * 256) {
    size_t base = i * 8;
    int c = (int)(base & 63);
    bfrag8 xv = *reinterpret_cast<const bfrag8*>(&X[base]);
    float4 d0 = *reinterpret_cast<float4*>(&D[base]);
    float4 d1 = *reinterpret_cast<float4*>(&D[base + 4]);
    float o[8];
#pragma unroll
    for (int j = 0; j < 8; j++) {
      float y = (bf2f((unsigned short)xv[j]) - mean[c + j]) * scal[c + j];
      y = y > 0.f ? y : 0.f;
      float dv = (j < 4) ? (&d0.x)[j] : (&d1.x)[j - 4];
      o[j] = dv + y;
    }
    d0 = make_float4(o[0], o[1], o[2], o[3]);
    d1 = make_float4(o[4], o[5], o[6], o[7]);
    *reinterpret_cast<float4*>(&D[base])     = d0;
    *reinterpret_cast<float4*>(&D[base + 4]) = d1;
    bfrag8 pb;
#pragma unroll
    for (int j = 0; j < 8; j++) pb[j] = (short)f2bf(o[j]);
    *reinterpret_cast<bfrag8*>(&Dbf[base]) = pb;
  }
}

// ---------------- orchestration ----------------

static inline int tiles_of(int M, int R) { return (M + R - 1) / R; }
static inline int imin(int a, int b) { return a < b ? a : b; }

extern "C" void kernel_launch(void* const* d_in, const int* in_sizes, int n_in,
                              void* d_out, int out_size, void* d_ws, size_t ws_size,
                              hipStream_t stream) {
  const float* xs      = (const float*)d_in[0];
  const float* nn1_w1  = (const float*)d_in[1];
  const float* nn1_b1  = (const float*)d_in[2];
  const float* nn1_w2  = (const float*)d_in[3];
  const float* nn1_b2  = (const float*)d_in[4];
  const float* nn2_w1  = (const float*)d_in[5];
  const float* nn2_b1  = (const float*)d_in[6];
  const float* nn2_w2  = (const float*)d_in[7];
  const float* nn2_b2  = (const float*)d_in[8];
  const float* l1_w    = (const float*)d_in[9];
  const float* l1_b    = (const float*)d_in[10];
  const float* l2_w    = (const float*)d_in[11];
  const float* l2_b    = (const float*)d_in[12];
  const float* l3_w    = (const float*)d_in[13];
  const float* l3_b    = (const float*)d_in[14];
  const float* l4_w    = (const float*)d_in[15];
  const float* l4_b    = (const float*)d_in[16];
  const float* out_w1  = (const float*)d_in[17];
  const float* out_b1  = (const float*)d_in[18];
  const float* out_w2  = (const float*)d_in[19];
  const float* out_b2  = (const float*)d_in[20];
  const int*   src     = (const int*)d_in[21];
  const int*   dst     = (const int*)d_in[22];

  float* out = (float*)d_out;

  unsigned short* u     = (unsigned short*)d_ws;
  unsigned short* t1    = u;
  unsigned short* rin   = t1    + (size_t)NTOT * 64;
  unsigned short* x32   = rin   + (size_t)NLEFT * 64;
  unsigned short* ri32  = x32   + (size_t)NTOT * 32;
  unsigned short* li32  = ri32  + (size_t)NLEFT * 32;
  unsigned short* rli32 = li32  + (size_t)NRIGHT * 32;
  unsigned short* outbf = rli32 + (size_t)NRIGHT * 32;
  float* stats = (float*)(outbf + (size_t)NTOT * 64);
  int*   cntL  = (int*)(stats + 20 * 128);
  int*   cntR  = cntL + NLEFT;
  int*   oL    = cntR + NRIGHT;
  int*   oR    = oL + (NLEFT + 1);
  int*   curL  = oR + (NRIGHT + 1);
  int*   curR  = curL + NLEFT;
  int*   part  = curR + NRIGHT;
  int*   adjL  = part + 1024;
  int*   adjR  = adjL + NEDGE;
  unsigned short* wcvt = (unsigned short*)(adjR + NEDGE);

  dim3 B(256);
  const int NB1 = (NLEFT + 255) / 256;
  const float invL = 1.f / NLEFT, invT = 1.f / NTOT;
  const int tilesL = tiles_of(NLEFT, 32);
  const int GD = imin(tilesL, 768);      // persistent: 3 blocks/CU (LDS ~52KB)

  init_kernel<<<2048, B, 0, stream>>>(xs, out, outbf, stats, 20 * 128, cntL, cntR, curL, curR);
  wconv_kernel<<<448, B, 0, stream>>>(l2_w, nn2_w1, l4_w, l3_w, nn2_w2, nn1_w1, l1_w,
                                      nn1_w2, out_w1, out_w2, wcvt);
  count_kernel<<<2048, B, 0, stream>>>(src, dst, cntL, cntR);
  scan1_kernel<<<NB1, B, 0, stream>>>(cntL, NLEFT, part);
  scan2_kernel<<<1, 1024, 0, stream>>>(part, NB1);
  scan3_kernel<<<NB1, B, 0, stream>>>(cntL, NLEFT, part, oL);
  scan1_kernel<<<NB1, B, 0, stream>>>(cntR, NRIGHT, part);
  scan2_kernel<<<1, 1024, 0, stream>>>(part, NB1);
  scan3_kernel<<<NB1, B, 0, stream>>>(cntR, NRIGHT, part, oR);
  fill_kernel<<<2048, B, 0, stream>>>(src, dst, oL, oR, curL, curR, adjL, adjR);

  for (int l = 0; l < 2; l++) {
    const float* p_nn1_b1 = nn1_b1 + (size_t)l * 64;
    const float* p_nn1_b2 = nn1_b2 + (size_t)l * 64;
    const float* p_nn2_b1 = nn2_b1 + (size_t)l * 64;
    const float* p_nn2_b2 = nn2_b2 + (size_t)l * 64;
    const float* p_l1_b   = l1_b + (size_t)l * 32;
    const float* p_l2_b   = l2_b + (size_t)l * 32;
    const float* p_l3_b   = l3_b + (size_t)l * 32;
    const float* p_l4_b   = l4_b + (size_t)l * 32;
    const float* p_out_b1 = out_b1 + (size_t)l * 64;
    const float* p_out_b2 = out_b2 + (size_t)l * 64;
    const unsigned short* wc = wcvt + (size_t)l * WC_PER_L;

    float* S = stats + (size_t)l * 10 * 128;
    auto ST = [&](int s) { return S + (size_t)s * 128; };

    // a+b+c1) gather right_info; ri=l2->s0; rin=nn2_w1->s1 (fused dual, persistent)
    gmm_mfma<32, 64, false><<<GD, 512, 0, stream>>>(
        outbf + (size_t)NLEFT * 64, oL, adjL, NLEFT, nullptr, 0.f,
        wc + WC_G1, p_l2_b, ri32, ST(0), p_nn2_b1, rin, ST(1));
    // c2) rin = nn2_w2(bnrelu(rin,s1)); s2
    mm_mfma<64, 64, 128, true><<<tiles_of(NLEFT, 128), B, 0, stream>>>(
        rin, wc + WC_NN2W2, p_nn2_b2, rin, NLEFT, ST(2), ST(1), invL);
    // f1+i) t1 = nn1_w1(outbf)->s4 ; x32 = l1(outbf)->s7
    mm2_mfma<<<tiles_of(NTOT, 128), B, 0, stream>>>(
        outbf, wc + WC_M2, p_nn1_b1, t1, ST(4), p_l1_b, x32, ST(7), NTOT);
    // f2) t1 = nn1_w2(bnrelu(t1,s4)); s5
    mm_mfma<64, 64, 128, true><<<tiles_of(NTOT, 128), B, 0, stream>>>(
        t1, wc + WC_NN1W2, p_nn1_b2, t1, NTOT, ST(5), ST(4), invT);
    // d+e & g+h fused: gather bnrelu(rin,s2) AND bnrelu(t1,s5) over adjR;
    //                  rli=l4->s3, li=l3->s6 (one adjacency pass)
    gmm2_mfma<<<GD, 512, 0, stream>>>(
        rin, ST(2), invL, t1, ST(5), invT, oR, adjR, NRIGHT,
        wc + WC_G2, p_l4_b, p_l3_b, rli32, ST(3), li32, ST(6));
    // j1) t1 = out_w1(h virtual concat); s8
    mmh_mfma<<<tiles_of(NTOT, 128), B, 0, stream>>>(
        x32, ri32, li32, rli32, ST(7), ST(0), ST(6), ST(3),
        wc + WC_OUTW1, p_out_b1, t1, ST(8));
    // j2) t1 = out_w2(bnrelu(t1,s8)); s9
    mm_mfma<64, 64, 128, true><<<tiles_of(NTOT, 128), B, 0, stream>>>(
        t1, wc + WC_OUTW2, p_out_b2, t1, NTOT, ST(9), ST(8), invT);
    // j3) out += relu(bn(t1,s9)); refresh bf16 mirror
    norm_add_kernel<<<2048, B, 0, stream>>>(t1, NTOT, ST(9), out, outbf);
  }
}